// Round 17
// baseline (193.862 us; speedup 1.0000x reference)
//
#include <hip/hip_runtime.h>
#include <cmath>

#define BB 8
#define HH 512
#define WW 512
#define HW (HH*WW)
#define RAD 15
#define SEG 16
#define EPS 0.001f
#define INV_K (1.0f/31.0f)
#define TROWS 16
#define NPX 272            // computed px per block: 256 out + 16 halo
#define XOFF (-8)
#define NCOL 271           // a/b columns per k_vhbox block (256 out + one-sided 15 halo)

typedef _Float16 h16x8 __attribute__((ext_vector_type(8)));
typedef _Float16 h16x4 __attribute__((ext_vector_type(4)));
typedef _Float16 h16x2 __attribute__((ext_vector_type(2)));
typedef float f32x4 __attribute__((ext_vector_type(4)));
typedef float f32x2 __attribute__((ext_vector_type(2)));
typedef int   i32x4 __attribute__((ext_vector_type(4)));

static __device__ inline int s3(int r) { return (r + 6) % 3; }   // r >= -6

// feats channel order: {I0, I1, I2, dark | tg, A0, A1, A2} -> W1 cmap {0,1,2,4,3,5,6,7}

// ------- gray + horizontal box (fp16 hq) + feats ch0-3; block 0 packs weights -------
__global__ __launch_bounds__(256) void k_gray_hbox4(const float* __restrict__ I,
                                                    const float* __restrict__ p,
                                                    const float* __restrict__ dark,
                                                    float* __restrict__ g,
                                                    h16x4* __restrict__ hq,
                                                    _Float16* __restrict__ feats,
                                                    const float* __restrict__ W1,
                                                    const float* __restrict__ W2,
                                                    _Float16* __restrict__ wf1,
                                                    _Float16* __restrict__ wf2) {
    __shared__ float sg[WW], sp[WW];
    int row = blockIdx.x;            // b*HH + y
    int b = row >> 9;
    int base = row * WW;
    const float* Ib = I + (size_t)b * 3 * HW + (size_t)(row & 511) * WW;
    const float* db = dark + (size_t)base;
    int tid = threadIdx.x;
    for (int x = tid; x < WW; x += 256) {
        float i0 = Ib[x], i1 = Ib[HW + x], i2 = Ib[2 * HW + x];
        float gv = 0.299f * i0 + 0.587f * i1 + 0.114f * i2;
        sg[x] = gv; sp[x] = p[base + x];
        g[base + x] = gv;
        h16x4 v;
        v[0] = (_Float16)i0; v[1] = (_Float16)i1; v[2] = (_Float16)i2;
        v[3] = (_Float16)db[x];
        *(h16x4*)(feats + ((size_t)base + x) * 8) = v;
    }
    __syncthreads();
    for (int x = tid; x < WW; x += 256) {
        float s0 = 0.f, s1 = 0.f, s2 = 0.f, s3v = 0.f;
        int lo = x - RAD < 0 ? 0 : x - RAD;
        int hi = x + RAD >= WW ? WW - 1 : x + RAD;
        for (int i = lo; i <= hi; ++i) {
            float gv = sg[i], pv = sp[i];
            s0 += gv; s1 += pv; s2 += gv * pv; s3v += gv * gv;
        }
        h16x4 o;
        o[0] = (_Float16)(s0 * INV_K); o[1] = (_Float16)(s1 * INV_K);
        o[2] = (_Float16)(s2 * INV_K); o[3] = (_Float16)(s3v * INV_K);
        hq[base + x] = o;
    }
    // ---- weight fragment prepack (block 0, first wave) ----
    if (blockIdx.x == 0 && tid < 64) {
        int lane = tid;
        int j = lane & 15, gg = lane >> 4;
        const int cmap[8] = {0, 1, 2, 4, 3, 5, 6, 7};
#pragma unroll
        for (int cg = 0; cg < 2; ++cg)
#pragma unroll
            for (int t = 0; t < 3; ++t) {
                int s = t * 4 + gg;
                h16x8 w;
#pragma unroll
                for (int i = 0; i < 8; ++i)
                    w[i] = (s < 9) ? (_Float16)W1[(cg * 16 + j) * 72 + cmap[i] * 9 + s]
                                   : (_Float16)0.f;
                *(h16x8*)(wf1 + ((cg * 3 + t) * 64 + lane) * 8) = w;
            }
        int ci0 = gg * 8;
#pragma unroll
        for (int s = 0; s < 9; ++s) {
            h16x8 w;
#pragma unroll
            for (int i = 0; i < 8; ++i)
                w[i] = (_Float16)W2[j * 288 + (ci0 + i) * 9 + s];
            *(h16x8*)(wf2 + (s * 64 + lane) * 8) = w;
        }
    }
}

// ------- merged vertical box(hq) -> a,b (fp32) -> horizontal box -> hab fp16 -------
__global__ __launch_bounds__(256) void k_vhbox(const h16x4* __restrict__ hq,
                                               h16x2* __restrict__ hab) {
    __shared__ float sa[2][NCOL + 1], sb[2][NCOL + 1];
    int tid = threadIdx.x;
    int X0 = blockIdx.x * 256;
    int b = blockIdx.y;
    int y0 = blockIdx.z * SEG;
    int xa0 = (X0 == 0) ? 0 : (WW - NCOL);     // 0 or 241
    int pbase = b * HW;

    int c0 = xa0 + tid;                        // owned col 1
    int c1 = xa0 + 256 + tid;                  // owned col 2 (tid < 15)
    bool has2 = (tid < NCOL - 256);

    f32x4 s0 = {0.f, 0.f, 0.f, 0.f}, s1 = {0.f, 0.f, 0.f, 0.f};
    int r0 = y0 - RAD < 0 ? 0 : y0 - RAD;
    for (int r = r0; r < y0 + RAD; ++r) {
        h16x4 v = hq[pbase + r * WW + c0];
        s0[0] += (float)v[0]; s0[1] += (float)v[1]; s0[2] += (float)v[2]; s0[3] += (float)v[3];
        if (has2) {
            h16x4 w = hq[pbase + r * WW + c1];
            s1[0] += (float)w[0]; s1[1] += (float)w[1]; s1[2] += (float)w[2]; s1[3] += (float)w[3];
        }
    }
    for (int y = y0; y < y0 + SEG; ++y) {
        if (y + RAD < HH) {
            h16x4 v = hq[pbase + (y + RAD) * WW + c0];
            s0[0] += (float)v[0]; s0[1] += (float)v[1]; s0[2] += (float)v[2]; s0[3] += (float)v[3];
            if (has2) {
                h16x4 w = hq[pbase + (y + RAD) * WW + c1];
                s1[0] += (float)w[0]; s1[1] += (float)w[1]; s1[2] += (float)w[2]; s1[3] += (float)w[3];
            }
        }
        int buf = y & 1;
        {
            float mI = s0[0] * INV_K, mP = s0[1] * INV_K, mIp = s0[2] * INV_K, mII = s0[3] * INV_K;
            float cov = mIp - mI * mP;
            float var = mII - mI * mI;
            float av = cov / (var + EPS);
            sa[buf][tid] = av;
            sb[buf][tid] = mP - av * mI;
        }
        if (has2) {
            float mI = s1[0] * INV_K, mP = s1[1] * INV_K, mIp = s1[2] * INV_K, mII = s1[3] * INV_K;
            float cov = mIp - mI * mP;
            float var = mII - mI * mI;
            float av = cov / (var + EPS);
            sa[buf][256 + tid] = av;
            sb[buf][256 + tid] = mP - av * mI;
        }
        __syncthreads();
        // horizontal 31-tap for output px x = X0 + tid  -> hab (second vbox runs later)
        int x = X0 + tid;
        int lo = (x - RAD < 0 ? 0 : x - RAD) - xa0;
        int hi = (x + RAD > WW - 1 ? WW - 1 : x + RAD) - xa0;
        float ha = 0.f, hb = 0.f;
        for (int i = lo; i <= hi; ++i) { ha += sa[buf][i]; hb += sb[buf][i]; }
        h16x2 o;
        o[0] = (_Float16)(ha * INV_K); o[1] = (_Float16)(hb * INV_K);
        hab[pbase + y * WW + x] = o;
        if (y - RAD >= 0) {
            h16x4 v = hq[pbase + (y - RAD) * WW + c0];
            s0[0] -= (float)v[0]; s0[1] -= (float)v[1]; s0[2] -= (float)v[2]; s0[3] -= (float)v[3];
            if (has2) {
                h16x4 w = hq[pbase + (y - RAD) * WW + c1];
                s1[0] -= (float)w[0]; s1[1] -= (float)w[1]; s1[2] -= (float)w[2]; s1[3] -= (float)w[3];
            }
        }
    }
}

// ------- vertical box of hab (fp16) + t_guided -> tg fp32 + feats ch4-7 -------
__global__ __launch_bounds__(256) void k_vbox2_tg(const h16x2* __restrict__ hab,
                                                  const float* __restrict__ g,
                                                  const float* __restrict__ A,
                                                  float* __restrict__ tg,
                                                  _Float16* __restrict__ feats) {
    int x = blockIdx.x * 256 + threadIdx.x;
    int b = blockIdx.y;
    int y0 = blockIdx.z * SEG;
    int pbase = b * HW + x;
    _Float16 A0 = (_Float16)A[b * 3 + 0], A1 = (_Float16)A[b * 3 + 1], A2 = (_Float16)A[b * 3 + 2];
    f32x2 s = { 0.f, 0.f };
    int r0 = y0 - RAD < 0 ? 0 : y0 - RAD;
    for (int r = r0; r < y0 + RAD; ++r) {
        h16x2 v = hab[pbase + r * WW];
        s[0] += (float)v[0]; s[1] += (float)v[1];
    }
    for (int y = y0; y < y0 + SEG; ++y) {
        if (y + RAD < HH) {
            h16x2 v = hab[pbase + (y + RAD) * WW];
            s[0] += (float)v[0]; s[1] += (float)v[1];
        }
        int o = pbase + y * WW;
        float val = (s[0] * INV_K) * g[o] + (s[1] * INV_K);
        tg[o] = val;
        h16x4 fv;
        fv[0] = (_Float16)val; fv[1] = A0; fv[2] = A1; fv[3] = A2;
        *(h16x4*)(feats + (size_t)o * 8 + 4) = fv;
        if (y - RAD >= 0) {
            h16x2 v = hab[pbase + (y - RAD) * WW];
            s[0] -= (float)v[0]; s[1] -= (float)v[1];
        }
    }
}

// ---------------- fused conv1+conv2+conv3, single barrier per row ----------------
// h1 LDS row: [NPX px][32 ch] fp16; 16B granule c (=ch/8) at sp = c ^ ((lp>>1)&3)
static __device__ inline h16x8 ld_h1(const _Float16* hrow, int lp, int c) {
    int sp = c ^ ((lp >> 1) & 3);
    return *(const h16x8*)(hrow + lp * 32 + sp * 8);
}
static __device__ inline void st_h1(_Float16* hrow, int lp, int u, h16x4 o) {   // u = ch/4
    int sp = (u >> 1) ^ ((lp >> 1) & 3);
    *(h16x4*)(hrow + lp * 32 + sp * 8 + (u & 1) * 4) = o;
}
// h2 LDS row: [NPX px][16 ch] fp16; granule c at sp = c ^ ((lp>>2)&1)
static __device__ inline void st_h2(_Float16* hrow, int lp, int u, h16x4 o) {   // u = ch/4
    int sp = (u >> 1) ^ ((lp >> 2) & 1);
    *(h16x4*)(hrow + lp * 16 + sp * 8 + (u & 1) * 4) = o;
}

static __device__ inline void load_b1(const _Float16* fb, int r1, int X0, int g,
                                      int j, int gq, h16x8 Bg[3]) {
    const h16x8 z = {0,0,0,0,0,0,0,0};
    bool xedgeG = (X0 == 0 && g == 0) || (X0 == 256 && g == 16);
    int gxb = X0 + XOFF + g * 16 + j;
    if (!xedgeG && r1 >= 1 && r1 <= 509) {
#pragma unroll
        for (int t = 0; t < 3; ++t) {
            int s = t * 4 + gq;
            int dy = s / 3 - 1, dx = s - (s / 3) * 3 - 1;
            Bg[t] = *(const h16x8*)(fb + ((size_t)(r1 + dy) * WW + (gxb + dx)) * 8);
        }
    } else {
#pragma unroll
        for (int t = 0; t < 3; ++t) {
            int s = t * 4 + gq;
            int dy = s / 3 - 1, dx = s - (s / 3) * 3 - 1;
            int yy = r1 + dy, xx = gxb + dx;
            bool ok = (s < 9) && yy >= 0 && yy < HH && xx >= 0 && xx < WW;
            int yc = yy < 0 ? 0 : (yy > HH - 1 ? HH - 1 : yy);
            int xc = xx < 0 ? 0 : (xx > WW - 1 ? WW - 1 : xx);
            h16x8 v = *(const h16x8*)(fb + ((size_t)yc * WW + xc) * 8);
            Bg[t] = ok ? v : z;
        }
    }
}

__global__ __launch_bounds__(512, 2) void k_cnn_fused(const _Float16* __restrict__ feats,
                                                      const _Float16* __restrict__ wf1,
                                                      const _Float16* __restrict__ wf2,
                                                      const float* __restrict__ b1,
                                                      const float* __restrict__ b2,
                                                      const float* __restrict__ W3,
                                                      const float* __restrict__ b3,
                                                      const float* __restrict__ tg,
                                                      float* __restrict__ out) {
    __shared__ _Float16 h1s[3][NPX * 32];    // 52,224 B
    __shared__ _Float16 h2s2[2][NPX * 16];   // 17,408 B (slot parity = row & 1)
    __shared__ h16x8 wf1s[6 * 64];           //  6,144 B
    __shared__ h16x2 w3s[72];
    __shared__ float sB[48];                 // b1[32], b2[16]
    __shared__ float w3bias;

    int tid = threadIdx.x;
    int lane = tid & 63, wave = tid >> 6;
    int j = lane & 15, gq = lane >> 4;
    int b = blockIdx.y;
    int X0 = (blockIdx.x & 1) * 256;
    int y0 = (blockIdx.x >> 1) * TROWS;
    const _Float16* fb = feats + (size_t)b * HW * 8;
    const float* tgb = tg + (size_t)b * HW;
    float* outb = out + (size_t)b * HW;

    // stage wf1 into LDS (384 x 16B), wA2 into regs
    for (int q = tid; q < 384; q += 512)
        ((i32x4*)wf1s)[q] = ((const i32x4*)wf1)[q];
    const h16x8* wf2v = (const h16x8*)wf2;
    h16x8 wA2[9];
#pragma unroll
    for (int s = 0; s < 9; ++s) wA2[s] = wf2v[s * 64 + lane];
    if (tid < 72) {
        int s = tid >> 3, u = tid & 7;
        h16x2 w;
        w[0] = (_Float16)W3[(2 * u) * 9 + s];
        w[1] = (_Float16)W3[(2 * u + 1) * 9 + s];
        w3s[tid] = w;
    } else if (tid < 104) {
        sB[tid - 72] = b1[tid - 72];
    } else if (tid < 120) {
        sB[32 + tid - 104] = b2[tid - 104];
    } else if (tid == 120) w3bias = b3[0];
    __syncthreads();

    int g0 = wave * 2;
    const h16x8 z16 = {0,0,0,0,0,0,0,0};
    h16x8 Bv[2][3];                  // conv1 B prefetch, groups {g0, g0+1}
    h16x8 Bg[3];                     // g16 conv1 B (wave 5 — conv2-scatter for g16 is wave 4)
    f32x4 cA[2] = {}, cB[2] = {}, cC[2] = {};   // conv2 scatter accs
    f32x4 gA = {}, gB = {}, gC = {};            // g16 scatter accs (wave 4)
    int c3px = tid >> 1, c3h = tid & 1;
    float accN = 0.f, accC3 = 0.f;

    for (int i = 0; i < TROWS + 6; ++i) {       // 22 iterations, 1 barrier each
        int r1 = y0 + i - 2;          // conv1 produces h1[r1]
        int rp = y0 + i - 3;          // conv2-scatter consumes h1[rp]
        int r2 = y0 + i - 4;          // h2 row completed + stored
        int R  = y0 + i - 5;          // h2 row conv3 reads (written last iter)
        bool do_h1 = (i <= TROWS + 3) && (r1 >= 0) && (r1 <= 511);
        bool do_rp = (i >= 1) && (i <= TROWS + 4) && (rp >= 0) && (rp <= 511);
        bool st_r2 = (i <= TROWS + 4) && (r2 >= 0) && (r2 <= 511);
        bool rd_R  = (R >= 0) && (R <= 511);

        // ---- A: issue conv1 global loads + tg prefetch (drain under B/C/D) ----
        if (do_h1) {
#pragma unroll
            for (int k = 0; k < 2; ++k)
                load_b1(fb, r1, X0, g0 + k, j, gq, Bv[k]);
            if (wave == 5) load_b1(fb, r1, X0, 16, j, gq, Bg);
        }
        float tgv = 0.f;
        int oOut = (y0 + i - 6) * WW + X0 + c3px;
        if (i >= 6 && c3h == 0) tgv = tgb[oOut];

        // ---- B: conv2 scatter — read h1[rp] once, update 3 row-accs ----
        f32x4 bias2v = *(const f32x4*)(sB + 32 + gq * 4);
#pragma unroll
        for (int k = 0; k < 2; ++k) {
            cA[k] = cB[k]; cB[k] = cC[k]; cC[k] = bias2v;
        }
        if (wave == 4) { gA = gB; gB = gC; gC = bias2v; }
        if (do_rp) {
            const _Float16* hrow = h1s[s3(rp)];
#pragma unroll
            for (int k = 0; k < 2; ++k) {
                int lpb = (g0 + k) * 16 + j;
#pragma unroll
                for (int dx = 0; dx < 3; ++dx) {
                    int lpx = lpb + dx - 1;
                    h16x8 v;
                    if (wave == 0 && k == 0) {
                        int lpc = lpx < 0 ? 0 : lpx;
                        v = ld_h1(hrow, lpc, gq);
                        if (X0 == 0) v = (lpx >= 8) ? v : z16;   // src x >= 0
                    } else {
                        v = ld_h1(hrow, lpx, gq);
                    }
                    cC[k] = __builtin_amdgcn_mfma_f32_16x16x32_f16(wA2[0 + dx], v, cC[k], 0, 0, 0);
                    cB[k] = __builtin_amdgcn_mfma_f32_16x16x32_f16(wA2[3 + dx], v, cB[k], 0, 0, 0);
                    cA[k] = __builtin_amdgcn_mfma_f32_16x16x32_f16(wA2[6 + dx], v, cA[k], 0, 0, 0);
                }
            }
            if (wave == 4) {                      // group 16 scatter
                int lpb = 256 + j;
#pragma unroll
                for (int dx = 0; dx < 3; ++dx) {
                    int lpx = lpb + dx - 1;       // 255..272
                    int lpc = lpx > NPX - 1 ? NPX - 1 : lpx;
                    h16x8 v = ld_h1(hrow, lpc, gq);
                    if (X0 == 256 && lpx > 263) v = z16;   // src x < WW
                    gC = __builtin_amdgcn_mfma_f32_16x16x32_f16(wA2[0 + dx], v, gC, 0, 0, 0);
                    gB = __builtin_amdgcn_mfma_f32_16x16x32_f16(wA2[3 + dx], v, gB, 0, 0, 0);
                    gA = __builtin_amdgcn_mfma_f32_16x16x32_f16(wA2[6 + dx], v, gA, 0, 0, 0);
                }
            }
        }

        // ---- C: store completed h2 row r2 (slot r2&1; conv3 reads slot R&1) ----
        if (st_r2) {
            _Float16* h2row = h2s2[r2 & 1];
#pragma unroll
            for (int k = 0; k < 2; ++k) {
                h16x4 o;
#pragma unroll
                for (int r = 0; r < 4; ++r) o[r] = (_Float16)fmaxf(cA[k][r], 0.f);
                st_h2(h2row, (g0 + k) * 16 + j, gq, o);
            }
            if (wave == 4) {
                h16x4 o;
#pragma unroll
                for (int r = 0; r < 4; ++r) o[r] = (_Float16)fmaxf(gA[r], 0.f);
                st_h2(h2row, 256 + j, gq, o);
            }
        }

        // ---- D: conv3 running-partials on h2 row R (written last iter) ----
        {
            float d0 = 0.f, d1 = 0.f, d2 = 0.f;
            if (rd_R) {
                const _Float16* hrow = h2s2[R & 1];
#pragma unroll
                for (int dx = 0; dx < 3; ++dx) {
                    int xim = X0 + c3px + dx - 1;
                    if (xim >= 0 && xim < WW) {
                        int lpx = c3px + 8 + dx - 1;
                        int sp = c3h ^ ((lpx >> 2) & 1);
                        h16x8 v = *(const h16x8*)(hrow + lpx * 16 + sp * 8);
#pragma unroll
                        for (int q = 0; q < 4; ++q) {
                            h16x2 pv = { v[2 * q], v[2 * q + 1] };
                            d0 = __builtin_amdgcn_fdot2(pv, w3s[(0 + dx) * 8 + 4 * c3h + q], d0, false);
                            d1 = __builtin_amdgcn_fdot2(pv, w3s[(3 + dx) * 8 + 4 * c3h + q], d1, false);
                            d2 = __builtin_amdgcn_fdot2(pv, w3s[(6 + dx) * 8 + 4 * c3h + q], d2, false);
                        }
                    }
                }
            }
            if (i >= 6) {
                float accv = accC3 + d2;
                float full = accv + __shfl_xor(accv, 1) + w3bias;
                if (c3h == 0) {
                    float sg = 1.f / (1.f + expf(-full));
                    float tf = 0.7f * tgv + 0.3f * sg;
                    outb[oOut] = fminf(fmaxf(tf, 0.f), 1.f);
                }
            }
            accC3 = accN + d1;
            accN = d0;
        }

        // ---- E: conv1 MFMA (Bv drained) + store h1 row r1 ----
        if (do_h1) {
            h16x8 w1[2][3];
#pragma unroll
            for (int cg = 0; cg < 2; ++cg)
#pragma unroll
                for (int t = 0; t < 3; ++t) w1[cg][t] = wf1s[(cg * 3 + t) * 64 + lane];
            _Float16* h1row = h1s[s3(r1)];
            f32x4 b1lo = *(const f32x4*)(sB + gq * 4);
            f32x4 b1hi = *(const f32x4*)(sB + 16 + gq * 4);
#pragma unroll
            for (int k = 0; k < 2; ++k) {
                f32x4 a1[2] = { b1lo, b1hi };
#pragma unroll
                for (int t = 0; t < 3; ++t)
#pragma unroll
                    for (int cg = 0; cg < 2; ++cg)
                        a1[cg] = __builtin_amdgcn_mfma_f32_16x16x32_f16(w1[cg][t], Bv[k][t], a1[cg], 0, 0, 0);
                int lp = (g0 + k) * 16 + j;
#pragma unroll
                for (int cg = 0; cg < 2; ++cg) {
                    h16x4 o;
#pragma unroll
                    for (int r = 0; r < 4; ++r) o[r] = (_Float16)fmaxf(a1[cg][r], 0.f);
                    st_h1(h1row, lp, cg * 4 + gq, o);
                }
            }
            if (wave == 5) {                      // g16 conv1 (off wave 4)
                f32x4 a1[2] = { b1lo, b1hi };
#pragma unroll
                for (int t = 0; t < 3; ++t)
#pragma unroll
                    for (int cg = 0; cg < 2; ++cg)
                        a1[cg] = __builtin_amdgcn_mfma_f32_16x16x32_f16(w1[cg][t], Bg[t], a1[cg], 0, 0, 0);
                int lp = 256 + j;
#pragma unroll
                for (int cg = 0; cg < 2; ++cg) {
                    h16x4 o;
#pragma unroll
                    for (int r = 0; r < 4; ++r) o[r] = (_Float16)fmaxf(a1[cg][r], 0.f);
                    st_h1(h1row, lp, cg * 4 + gq, o);
                }
            }
        }
        __syncthreads();
    }
}

extern "C" void kernel_launch(void* const* d_in, const int* in_sizes, int n_in,
                              void* d_out, int out_size, void* d_ws, size_t ws_size,
                              hipStream_t stream) {
    const float* I    = (const float*)d_in[0];
    const float* t0   = (const float*)d_in[1];
    const float* dark = (const float*)d_in[2];
    const float* A    = (const float*)d_in[3];
    const float* W1   = (const float*)d_in[4];
    const float* b1   = (const float*)d_in[5];
    const float* W2   = (const float*)d_in[6];
    const float* b2   = (const float*)d_in[7];
    const float* W3   = (const float*)d_in[8];
    const float* b3   = (const float*)d_in[9];
    float* out = (float*)d_out;
    float* ws  = (float*)d_ws;

    const size_t P = (size_t)BB * HW;       // 2M floats = 8 MB
    float* tg       = ws;                       // [0,P)    fp32
    _Float16* feats = (_Float16*)(ws + P);      // [P,5P)   fp16 [B][HW][8]
    float* g        = ws + 5 * P;               // [5P,6P)  fp32
    h16x4* hq       = (h16x4*)(ws + 6 * P);     // [6P,8P)  8B/px
    h16x2* hab      = (h16x2*)(ws + 8 * P);     // [8P,9P)  4B/px
    _Float16* wf1   = (_Float16*)(ws + 9 * P);  // 3072 halves
    _Float16* wf2   = wf1 + 6 * 64 * 8;         // 4608 halves

    k_gray_hbox4<<<BB * HH, 256, 0, stream>>>(I, t0, dark, g, hq, feats, W1, W2, wf1, wf2);
    dim3 gb(2, BB, HH / SEG);
    k_vhbox<<<gb, 256, 0, stream>>>(hq, hab);
    k_vbox2_tg<<<gb, 256, 0, stream>>>(hab, g, A, tg, feats);

    dim3 gf(64, BB);                        // 32 y-tiles x 2 x-halves x 8 batches
    k_cnn_fused<<<gf, 512, 0, stream>>>(feats, wf1, wf2, b1, b2, W3, b3, tg, out);
}

// Round 18
// 181.440 us; speedup vs baseline: 1.0685x; 1.0685x over previous
//
#include <hip/hip_runtime.h>
#include <cmath>

#define BB 8
#define HH 512
#define WW 512
#define HW (HH*WW)
#define RAD 15
#define SEG 16
#define EPS 0.001f
#define INV_K (1.0f/31.0f)
#define TROWS 16
#define NPX 272            // computed px per block: 256 out + 16 halo
#define XOFF (-8)

typedef _Float16 h16x8 __attribute__((ext_vector_type(8)));
typedef _Float16 h16x4 __attribute__((ext_vector_type(4)));
typedef _Float16 h16x2 __attribute__((ext_vector_type(2)));
typedef float f32x4 __attribute__((ext_vector_type(4)));
typedef float f32x2 __attribute__((ext_vector_type(2)));
typedef int   i32x4 __attribute__((ext_vector_type(4)));

static __device__ inline int s3(int r) { return (r + 6) % 3; }   // r >= -6

// feats channel order: {I0, I1, I2, dark | tg, A0, A1, A2} -> W1 cmap {0,1,2,4,3,5,6,7}

// ------- gray + horizontal box (fp16 hq) + feats ch0-3; block 0 packs weights -------
__global__ __launch_bounds__(256) void k_gray_hbox4(const float* __restrict__ I,
                                                    const float* __restrict__ p,
                                                    const float* __restrict__ dark,
                                                    float* __restrict__ g,
                                                    h16x4* __restrict__ hq,
                                                    _Float16* __restrict__ feats,
                                                    const float* __restrict__ W1,
                                                    const float* __restrict__ W2,
                                                    _Float16* __restrict__ wf1,
                                                    _Float16* __restrict__ wf2) {
    __shared__ float sg[WW], sp[WW];
    int row = blockIdx.x;            // b*HH + y
    int b = row >> 9;
    int base = row * WW;
    const float* Ib = I + (size_t)b * 3 * HW + (size_t)(row & 511) * WW;
    const float* db = dark + (size_t)base;
    int tid = threadIdx.x;
    for (int x = tid; x < WW; x += 256) {
        float i0 = Ib[x], i1 = Ib[HW + x], i2 = Ib[2 * HW + x];
        float gv = 0.299f * i0 + 0.587f * i1 + 0.114f * i2;
        sg[x] = gv; sp[x] = p[base + x];
        g[base + x] = gv;
        h16x4 v;
        v[0] = (_Float16)i0; v[1] = (_Float16)i1; v[2] = (_Float16)i2;
        v[3] = (_Float16)db[x];
        *(h16x4*)(feats + ((size_t)base + x) * 8) = v;
    }
    __syncthreads();
    for (int x = tid; x < WW; x += 256) {
        float s0 = 0.f, s1 = 0.f, s2 = 0.f, s3v = 0.f;
        int lo = x - RAD < 0 ? 0 : x - RAD;
        int hi = x + RAD >= WW ? WW - 1 : x + RAD;
        for (int i = lo; i <= hi; ++i) {
            float gv = sg[i], pv = sp[i];
            s0 += gv; s1 += pv; s2 += gv * pv; s3v += gv * gv;
        }
        h16x4 o;
        o[0] = (_Float16)(s0 * INV_K); o[1] = (_Float16)(s1 * INV_K);
        o[2] = (_Float16)(s2 * INV_K); o[3] = (_Float16)(s3v * INV_K);
        hq[base + x] = o;
    }
    // ---- weight fragment prepack (block 0, first wave) ----
    if (blockIdx.x == 0 && tid < 64) {
        int lane = tid;
        int j = lane & 15, gg = lane >> 4;
        const int cmap[8] = {0, 1, 2, 4, 3, 5, 6, 7};
#pragma unroll
        for (int cg = 0; cg < 2; ++cg)
#pragma unroll
            for (int t = 0; t < 3; ++t) {
                int s = t * 4 + gg;
                h16x8 w;
#pragma unroll
                for (int i = 0; i < 8; ++i)
                    w[i] = (s < 9) ? (_Float16)W1[(cg * 16 + j) * 72 + cmap[i] * 9 + s]
                                   : (_Float16)0.f;
                *(h16x8*)(wf1 + ((cg * 3 + t) * 64 + lane) * 8) = w;
            }
        int ci0 = gg * 8;
#pragma unroll
        for (int s = 0; s < 9; ++s) {
            h16x8 w;
#pragma unroll
            for (int i = 0; i < 8; ++i)
                w[i] = (_Float16)W2[j * 288 + (ci0 + i) * 9 + s];
            *(h16x8*)(wf2 + (s * 64 + lane) * 8) = w;
        }
    }
}

// ---------------- vertical box of hq (fp16), fused a/b -> ab fp16 ----------------
__global__ __launch_bounds__(256) void k_vbox4_ab(const h16x4* __restrict__ hq,
                                                  h16x2* __restrict__ ab) {
    int x = blockIdx.x * 256 + threadIdx.x;
    int b = blockIdx.y;
    int y0 = blockIdx.z * SEG;
    int pbase = b * HW + x;
    f32x4 s = { 0.f, 0.f, 0.f, 0.f };
    int r0 = y0 - RAD < 0 ? 0 : y0 - RAD;
    for (int r = r0; r < y0 + RAD; ++r) {
        h16x4 v = hq[pbase + r * WW];
        s[0] += (float)v[0]; s[1] += (float)v[1]; s[2] += (float)v[2]; s[3] += (float)v[3];
    }
    for (int y = y0; y < y0 + SEG; ++y) {
        if (y + RAD < HH) {
            h16x4 v = hq[pbase + (y + RAD) * WW];
            s[0] += (float)v[0]; s[1] += (float)v[1]; s[2] += (float)v[2]; s[3] += (float)v[3];
        }
        float mI = s[0] * INV_K, mP = s[1] * INV_K, mIp = s[2] * INV_K, mII = s[3] * INV_K;
        float cov = mIp - mI * mP;
        float var = mII - mI * mI;
        float av = cov / (var + EPS);
        float bv = mP - av * mI;
        h16x2 o;
        o[0] = (_Float16)av; o[1] = (_Float16)bv;
        ab[pbase + y * WW] = o;
        if (y - RAD >= 0) {
            h16x4 v = hq[pbase + (y - RAD) * WW];
            s[0] -= (float)v[0]; s[1] -= (float)v[1]; s[2] -= (float)v[2]; s[3] -= (float)v[3];
        }
    }
}

// ---------------- horizontal box of ab (fp16 in/out) ----------------
__global__ __launch_bounds__(256) void k_hbox2(const h16x2* __restrict__ ab,
                                               h16x2* __restrict__ hab) {
    __shared__ float sa[WW], sb[WW];
    int base = blockIdx.x * WW;
    int tid = threadIdx.x;
    for (int x = tid; x < WW; x += 256) {
        h16x2 v = ab[base + x];
        sa[x] = (float)v[0]; sb[x] = (float)v[1];
    }
    __syncthreads();
    for (int x = tid; x < WW; x += 256) {
        float s0 = 0.f, s1 = 0.f;
        int lo = x - RAD < 0 ? 0 : x - RAD;
        int hi = x + RAD >= WW ? WW - 1 : x + RAD;
        for (int i = lo; i <= hi; ++i) { s0 += sa[i]; s1 += sb[i]; }
        h16x2 o;
        o[0] = (_Float16)(s0 * INV_K); o[1] = (_Float16)(s1 * INV_K);
        hab[base + x] = o;
    }
}

// ------- vertical box of hab (fp16) + t_guided -> tg fp32 + feats ch4-7 -------
__global__ __launch_bounds__(256) void k_vbox2_tg(const h16x2* __restrict__ hab,
                                                  const float* __restrict__ g,
                                                  const float* __restrict__ A,
                                                  float* __restrict__ tg,
                                                  _Float16* __restrict__ feats) {
    int x = blockIdx.x * 256 + threadIdx.x;
    int b = blockIdx.y;
    int y0 = blockIdx.z * SEG;
    int pbase = b * HW + x;
    _Float16 A0 = (_Float16)A[b * 3 + 0], A1 = (_Float16)A[b * 3 + 1], A2 = (_Float16)A[b * 3 + 2];
    f32x2 s = { 0.f, 0.f };
    int r0 = y0 - RAD < 0 ? 0 : y0 - RAD;
    for (int r = r0; r < y0 + RAD; ++r) {
        h16x2 v = hab[pbase + r * WW];
        s[0] += (float)v[0]; s[1] += (float)v[1];
    }
    for (int y = y0; y < y0 + SEG; ++y) {
        if (y + RAD < HH) {
            h16x2 v = hab[pbase + (y + RAD) * WW];
            s[0] += (float)v[0]; s[1] += (float)v[1];
        }
        int o = pbase + y * WW;
        float val = (s[0] * INV_K) * g[o] + (s[1] * INV_K);
        tg[o] = val;
        h16x4 fv;
        fv[0] = (_Float16)val; fv[1] = A0; fv[2] = A1; fv[3] = A2;
        *(h16x4*)(feats + (size_t)o * 8 + 4) = fv;
        if (y - RAD >= 0) {
            h16x2 v = hab[pbase + (y - RAD) * WW];
            s[0] -= (float)v[0]; s[1] -= (float)v[1];
        }
    }
}

// ---------------- fused conv1+conv2+conv3, single barrier per row ----------------
// h1 LDS row: [NPX px][32 ch] fp16; 16B granule c (=ch/8) at sp = c ^ ((lp>>1)&3)
static __device__ inline h16x8 ld_h1(const _Float16* hrow, int lp, int c) {
    int sp = c ^ ((lp >> 1) & 3);
    return *(const h16x8*)(hrow + lp * 32 + sp * 8);
}
static __device__ inline void st_h1(_Float16* hrow, int lp, int u, h16x4 o) {   // u = ch/4
    int sp = (u >> 1) ^ ((lp >> 1) & 3);
    *(h16x4*)(hrow + lp * 32 + sp * 8 + (u & 1) * 4) = o;
}
// h2 LDS row: [NPX px][16 ch] fp16; granule c at sp = c ^ ((lp>>2)&1)
static __device__ inline void st_h2(_Float16* hrow, int lp, int u, h16x4 o) {   // u = ch/4
    int sp = (u >> 1) ^ ((lp >> 2) & 1);
    *(h16x4*)(hrow + lp * 16 + sp * 8 + (u & 1) * 4) = o;
}

static __device__ inline void load_b1(const _Float16* fb, int r1, int X0, int g,
                                      int j, int gq, h16x8 Bg[3]) {
    const h16x8 z = {0,0,0,0,0,0,0,0};
    bool xedgeG = (X0 == 0 && g == 0) || (X0 == 256 && g == 16);
    int gxb = X0 + XOFF + g * 16 + j;
    if (!xedgeG && r1 >= 1 && r1 <= 509) {
#pragma unroll
        for (int t = 0; t < 3; ++t) {
            int s = t * 4 + gq;
            int dy = s / 3 - 1, dx = s - (s / 3) * 3 - 1;
            Bg[t] = *(const h16x8*)(fb + ((size_t)(r1 + dy) * WW + (gxb + dx)) * 8);
        }
    } else {
#pragma unroll
        for (int t = 0; t < 3; ++t) {
            int s = t * 4 + gq;
            int dy = s / 3 - 1, dx = s - (s / 3) * 3 - 1;
            int yy = r1 + dy, xx = gxb + dx;
            bool ok = (s < 9) && yy >= 0 && yy < HH && xx >= 0 && xx < WW;
            int yc = yy < 0 ? 0 : (yy > HH - 1 ? HH - 1 : yy);
            int xc = xx < 0 ? 0 : (xx > WW - 1 ? WW - 1 : xx);
            h16x8 v = *(const h16x8*)(fb + ((size_t)yc * WW + xc) * 8);
            Bg[t] = ok ? v : z;
        }
    }
}

__global__ __launch_bounds__(512, 2) void k_cnn_fused(const _Float16* __restrict__ feats,
                                                      const _Float16* __restrict__ wf1,
                                                      const _Float16* __restrict__ wf2,
                                                      const float* __restrict__ b1,
                                                      const float* __restrict__ b2,
                                                      const float* __restrict__ W3,
                                                      const float* __restrict__ b3,
                                                      const float* __restrict__ tg,
                                                      float* __restrict__ out) {
    __shared__ _Float16 h1s[3][NPX * 32];    // 52,224 B
    __shared__ _Float16 h2s2[2][NPX * 16];   // 17,408 B (slot parity = row & 1)
    __shared__ h16x8 wf1s[6 * 64];           //  6,144 B
    __shared__ h16x2 w3s[72];
    __shared__ float sB[48];                 // b1[32], b2[16]
    __shared__ float w3bias;

    int tid = threadIdx.x;
    int lane = tid & 63, wave = tid >> 6;
    int j = lane & 15, gq = lane >> 4;
    int b = blockIdx.y;
    int X0 = (blockIdx.x & 1) * 256;
    int y0 = (blockIdx.x >> 1) * TROWS;
    const _Float16* fb = feats + (size_t)b * HW * 8;
    const float* tgb = tg + (size_t)b * HW;
    float* outb = out + (size_t)b * HW;

    // stage wf1 into LDS (384 x 16B), wA2 into regs
    for (int q = tid; q < 384; q += 512)
        ((i32x4*)wf1s)[q] = ((const i32x4*)wf1)[q];
    const h16x8* wf2v = (const h16x8*)wf2;
    h16x8 wA2[9];
#pragma unroll
    for (int s = 0; s < 9; ++s) wA2[s] = wf2v[s * 64 + lane];
    if (tid < 72) {
        int s = tid >> 3, u = tid & 7;
        h16x2 w;
        w[0] = (_Float16)W3[(2 * u) * 9 + s];
        w[1] = (_Float16)W3[(2 * u + 1) * 9 + s];
        w3s[tid] = w;
    } else if (tid < 104) {
        sB[tid - 72] = b1[tid - 72];
    } else if (tid < 120) {
        sB[32 + tid - 104] = b2[tid - 104];
    } else if (tid == 120) w3bias = b3[0];
    __syncthreads();

    int g0 = wave * 2;
    const h16x8 z16 = {0,0,0,0,0,0,0,0};
    h16x8 Bv[2][3];                  // conv1 B prefetch, groups {g0, g0+1}
    h16x8 Bg[3];                     // g16 conv1 B (wave 5 — conv2-scatter for g16 is wave 4)
    f32x4 cA[2] = {}, cB[2] = {}, cC[2] = {};   // conv2 scatter accs
    f32x4 gA = {}, gB = {}, gC = {};            // g16 scatter accs (wave 4)
    int c3px = tid >> 1, c3h = tid & 1;
    float accN = 0.f, accC3 = 0.f;

    for (int i = 0; i < TROWS + 6; ++i) {       // 22 iterations, 1 barrier each
        int r1 = y0 + i - 2;          // conv1 produces h1[r1]
        int rp = y0 + i - 3;          // conv2-scatter consumes h1[rp]
        int r2 = y0 + i - 4;          // h2 row completed + stored
        int R  = y0 + i - 5;          // h2 row conv3 reads (written last iter)
        bool do_h1 = (i <= TROWS + 3) && (r1 >= 0) && (r1 <= 511);
        bool do_rp = (i >= 1) && (i <= TROWS + 4) && (rp >= 0) && (rp <= 511);
        bool st_r2 = (i <= TROWS + 4) && (r2 >= 0) && (r2 <= 511);
        bool rd_R  = (R >= 0) && (R <= 511);

        // ---- A: issue conv1 global loads + tg prefetch (drain under B/C/D) ----
        if (do_h1) {
#pragma unroll
            for (int k = 0; k < 2; ++k)
                load_b1(fb, r1, X0, g0 + k, j, gq, Bv[k]);
            if (wave == 5) load_b1(fb, r1, X0, 16, j, gq, Bg);
        }
        float tgv = 0.f;
        int oOut = (y0 + i - 6) * WW + X0 + c3px;
        if (i >= 6 && c3h == 0) tgv = tgb[oOut];

        // ---- B: conv2 scatter — read h1[rp] once, update 3 row-accs ----
        f32x4 bias2v = *(const f32x4*)(sB + 32 + gq * 4);
#pragma unroll
        for (int k = 0; k < 2; ++k) {
            cA[k] = cB[k]; cB[k] = cC[k]; cC[k] = bias2v;
        }
        if (wave == 4) { gA = gB; gB = gC; gC = bias2v; }
        if (do_rp) {
            const _Float16* hrow = h1s[s3(rp)];
#pragma unroll
            for (int k = 0; k < 2; ++k) {
                int lpb = (g0 + k) * 16 + j;
#pragma unroll
                for (int dx = 0; dx < 3; ++dx) {
                    int lpx = lpb + dx - 1;
                    h16x8 v;
                    if (wave == 0 && k == 0) {
                        int lpc = lpx < 0 ? 0 : lpx;
                        v = ld_h1(hrow, lpc, gq);
                        if (X0 == 0) v = (lpx >= 8) ? v : z16;   // src x >= 0
                    } else {
                        v = ld_h1(hrow, lpx, gq);
                    }
                    cC[k] = __builtin_amdgcn_mfma_f32_16x16x32_f16(wA2[0 + dx], v, cC[k], 0, 0, 0);
                    cB[k] = __builtin_amdgcn_mfma_f32_16x16x32_f16(wA2[3 + dx], v, cB[k], 0, 0, 0);
                    cA[k] = __builtin_amdgcn_mfma_f32_16x16x32_f16(wA2[6 + dx], v, cA[k], 0, 0, 0);
                }
            }
            if (wave == 4) {                      // group 16 scatter
                int lpb = 256 + j;
#pragma unroll
                for (int dx = 0; dx < 3; ++dx) {
                    int lpx = lpb + dx - 1;       // 255..272
                    int lpc = lpx > NPX - 1 ? NPX - 1 : lpx;
                    h16x8 v = ld_h1(hrow, lpc, gq);
                    if (X0 == 256 && lpx > 263) v = z16;   // src x < WW
                    gC = __builtin_amdgcn_mfma_f32_16x16x32_f16(wA2[0 + dx], v, gC, 0, 0, 0);
                    gB = __builtin_amdgcn_mfma_f32_16x16x32_f16(wA2[3 + dx], v, gB, 0, 0, 0);
                    gA = __builtin_amdgcn_mfma_f32_16x16x32_f16(wA2[6 + dx], v, gA, 0, 0, 0);
                }
            }
        }

        // ---- C: store completed h2 row r2 (slot r2&1; conv3 reads slot R&1) ----
        if (st_r2) {
            _Float16* h2row = h2s2[r2 & 1];
#pragma unroll
            for (int k = 0; k < 2; ++k) {
                h16x4 o;
#pragma unroll
                for (int r = 0; r < 4; ++r) o[r] = (_Float16)fmaxf(cA[k][r], 0.f);
                st_h2(h2row, (g0 + k) * 16 + j, gq, o);
            }
            if (wave == 4) {
                h16x4 o;
#pragma unroll
                for (int r = 0; r < 4; ++r) o[r] = (_Float16)fmaxf(gA[r], 0.f);
                st_h2(h2row, 256 + j, gq, o);
            }
        }

        // ---- D: conv3 running-partials on h2 row R (written last iter) ----
        {
            float d0 = 0.f, d1 = 0.f, d2 = 0.f;
            if (rd_R) {
                const _Float16* hrow = h2s2[R & 1];
#pragma unroll
                for (int dx = 0; dx < 3; ++dx) {
                    int xim = X0 + c3px + dx - 1;
                    if (xim >= 0 && xim < WW) {
                        int lpx = c3px + 8 + dx - 1;
                        int sp = c3h ^ ((lpx >> 2) & 1);
                        h16x8 v = *(const h16x8*)(hrow + lpx * 16 + sp * 8);
#pragma unroll
                        for (int q = 0; q < 4; ++q) {
                            h16x2 pv = { v[2 * q], v[2 * q + 1] };
                            d0 = __builtin_amdgcn_fdot2(pv, w3s[(0 + dx) * 8 + 4 * c3h + q], d0, false);
                            d1 = __builtin_amdgcn_fdot2(pv, w3s[(3 + dx) * 8 + 4 * c3h + q], d1, false);
                            d2 = __builtin_amdgcn_fdot2(pv, w3s[(6 + dx) * 8 + 4 * c3h + q], d2, false);
                        }
                    }
                }
            }
            if (i >= 6) {
                float accv = accC3 + d2;
                float full = accv + __shfl_xor(accv, 1) + w3bias;
                if (c3h == 0) {
                    float sg = 1.f / (1.f + expf(-full));
                    float tf = 0.7f * tgv + 0.3f * sg;
                    outb[oOut] = fminf(fmaxf(tf, 0.f), 1.f);
                }
            }
            accC3 = accN + d1;
            accN = d0;
        }

        // ---- E: conv1 MFMA (Bv drained) + store h1 row r1 ----
        if (do_h1) {
            h16x8 w1[2][3];
#pragma unroll
            for (int cg = 0; cg < 2; ++cg)
#pragma unroll
                for (int t = 0; t < 3; ++t) w1[cg][t] = wf1s[(cg * 3 + t) * 64 + lane];
            _Float16* h1row = h1s[s3(r1)];
            f32x4 b1lo = *(const f32x4*)(sB + gq * 4);
            f32x4 b1hi = *(const f32x4*)(sB + 16 + gq * 4);
#pragma unroll
            for (int k = 0; k < 2; ++k) {
                f32x4 a1[2] = { b1lo, b1hi };
#pragma unroll
                for (int t = 0; t < 3; ++t)
#pragma unroll
                    for (int cg = 0; cg < 2; ++cg)
                        a1[cg] = __builtin_amdgcn_mfma_f32_16x16x32_f16(w1[cg][t], Bv[k][t], a1[cg], 0, 0, 0);
                int lp = (g0 + k) * 16 + j;
#pragma unroll
                for (int cg = 0; cg < 2; ++cg) {
                    h16x4 o;
#pragma unroll
                    for (int r = 0; r < 4; ++r) o[r] = (_Float16)fmaxf(a1[cg][r], 0.f);
                    st_h1(h1row, lp, cg * 4 + gq, o);
                }
            }
            if (wave == 5) {                      // g16 conv1 (off wave 4)
                f32x4 a1[2] = { b1lo, b1hi };
#pragma unroll
                for (int t = 0; t < 3; ++t)
#pragma unroll
                    for (int cg = 0; cg < 2; ++cg)
                        a1[cg] = __builtin_amdgcn_mfma_f32_16x16x32_f16(w1[cg][t], Bg[t], a1[cg], 0, 0, 0);
                int lp = 256 + j;
#pragma unroll
                for (int cg = 0; cg < 2; ++cg) {
                    h16x4 o;
#pragma unroll
                    for (int r = 0; r < 4; ++r) o[r] = (_Float16)fmaxf(a1[cg][r], 0.f);
                    st_h1(h1row, lp, cg * 4 + gq, o);
                }
            }
        }
        __syncthreads();
    }
}

extern "C" void kernel_launch(void* const* d_in, const int* in_sizes, int n_in,
                              void* d_out, int out_size, void* d_ws, size_t ws_size,
                              hipStream_t stream) {
    const float* I    = (const float*)d_in[0];
    const float* t0   = (const float*)d_in[1];
    const float* dark = (const float*)d_in[2];
    const float* A    = (const float*)d_in[3];
    const float* W1   = (const float*)d_in[4];
    const float* b1   = (const float*)d_in[5];
    const float* W2   = (const float*)d_in[6];
    const float* b2   = (const float*)d_in[7];
    const float* W3   = (const float*)d_in[8];
    const float* b3   = (const float*)d_in[9];
    float* out = (float*)d_out;
    float* ws  = (float*)d_ws;

    const size_t P = (size_t)BB * HW;       // 2M floats = 8 MB
    float* tg       = ws;                       // [0,P)    fp32
    _Float16* feats = (_Float16*)(ws + P);      // [P,5P)   fp16 [B][HW][8]
    float* g        = ws + 5 * P;               // [5P,6P)  fp32
    h16x4* hq       = (h16x4*)(ws + 6 * P);     // [6P,8P)  8B/px
    h16x2* ab       = (h16x2*)(ws + 8 * P);     // [8P,9P)  4B/px
    h16x2* hab      = (h16x2*)(ws + 9 * P);     // [9P,10P) 4B/px
    _Float16* wf1   = (_Float16*)(ws + 10 * P); // 3072 halves
    _Float16* wf2   = wf1 + 6 * 64 * 8;         // 4608 halves

    k_gray_hbox4<<<BB * HH, 256, 0, stream>>>(I, t0, dark, g, hq, feats, W1, W2, wf1, wf2);
    dim3 gv(WW / 256, BB, HH / SEG);
    k_vbox4_ab<<<gv, 256, 0, stream>>>(hq, ab);
    k_hbox2<<<BB * HH, 256, 0, stream>>>(ab, hab);
    k_vbox2_tg<<<gv, 256, 0, stream>>>(hab, g, A, tg, feats);

    dim3 gf(64, BB);                        // 32 y-tiles x 2 x-halves x 8 batches
    k_cnn_fused<<<gf, 512, 0, stream>>>(feats, wf1, wf2, b1, b2, W3, b3, tg, out);
}

// Round 19
// 177.679 us; speedup vs baseline: 1.0911x; 1.0212x over previous
//
#include <hip/hip_runtime.h>
#include <cmath>

#define BB 8
#define HH 512
#define WW 512
#define HW (HH*WW)
#define RAD 15
#define SEG 16
#define EPS 0.001f
#define INV_K (1.0f/31.0f)
#define TROWS 16
#define NPX 272            // computed px per block: 256 out + 16 halo
#define XOFF (-8)

typedef _Float16 h16x8 __attribute__((ext_vector_type(8)));
typedef _Float16 h16x4 __attribute__((ext_vector_type(4)));
typedef _Float16 h16x2 __attribute__((ext_vector_type(2)));
typedef float f32x4 __attribute__((ext_vector_type(4)));
typedef float f32x2 __attribute__((ext_vector_type(2)));
typedef int   i32x4 __attribute__((ext_vector_type(4)));

static __device__ inline int s3(int r) { return (r + 6) % 3; }   // r >= -6

// feats channel order: {I0, I1, I2, dark | tg, A0, A1, A2} -> W1 cmap {0,1,2,4,3,5,6,7}

// ------- gray + horizontal box (fp16 hq) + feats ch0-3; block 0 packs weights -------
__global__ __launch_bounds__(256) void k_gray_hbox4(const float* __restrict__ I,
                                                    const float* __restrict__ p,
                                                    const float* __restrict__ dark,
                                                    float* __restrict__ g,
                                                    h16x4* __restrict__ hq,
                                                    _Float16* __restrict__ feats,
                                                    const float* __restrict__ W1,
                                                    const float* __restrict__ W2,
                                                    _Float16* __restrict__ wf1,
                                                    _Float16* __restrict__ wf2) {
    __shared__ float sg[WW], sp[WW];
    int row = blockIdx.x;            // b*HH + y
    int b = row >> 9;
    int base = row * WW;
    const float* Ib = I + (size_t)b * 3 * HW + (size_t)(row & 511) * WW;
    const float* db = dark + (size_t)base;
    int tid = threadIdx.x;
    for (int x = tid; x < WW; x += 256) {
        float i0 = Ib[x], i1 = Ib[HW + x], i2 = Ib[2 * HW + x];
        float gv = 0.299f * i0 + 0.587f * i1 + 0.114f * i2;
        sg[x] = gv; sp[x] = p[base + x];
        g[base + x] = gv;
        h16x4 v;
        v[0] = (_Float16)i0; v[1] = (_Float16)i1; v[2] = (_Float16)i2;
        v[3] = (_Float16)db[x];
        *(h16x4*)(feats + ((size_t)base + x) * 8) = v;
    }
    __syncthreads();
    for (int x = tid; x < WW; x += 256) {
        float s0 = 0.f, s1 = 0.f, s2 = 0.f, s3v = 0.f;
        int lo = x - RAD < 0 ? 0 : x - RAD;
        int hi = x + RAD >= WW ? WW - 1 : x + RAD;
        for (int i = lo; i <= hi; ++i) {
            float gv = sg[i], pv = sp[i];
            s0 += gv; s1 += pv; s2 += gv * pv; s3v += gv * gv;
        }
        h16x4 o;
        o[0] = (_Float16)(s0 * INV_K); o[1] = (_Float16)(s1 * INV_K);
        o[2] = (_Float16)(s2 * INV_K); o[3] = (_Float16)(s3v * INV_K);
        hq[base + x] = o;
    }
    // ---- weight fragment prepack (block 0, first wave) ----
    if (blockIdx.x == 0 && tid < 64) {
        int lane = tid;
        int j = lane & 15, gg = lane >> 4;
        const int cmap[8] = {0, 1, 2, 4, 3, 5, 6, 7};
#pragma unroll
        for (int cg = 0; cg < 2; ++cg)
#pragma unroll
            for (int t = 0; t < 3; ++t) {
                int s = t * 4 + gg;
                h16x8 w;
#pragma unroll
                for (int i = 0; i < 8; ++i)
                    w[i] = (s < 9) ? (_Float16)W1[(cg * 16 + j) * 72 + cmap[i] * 9 + s]
                                   : (_Float16)0.f;
                *(h16x8*)(wf1 + ((cg * 3 + t) * 64 + lane) * 8) = w;
            }
        int ci0 = gg * 8;
#pragma unroll
        for (int s = 0; s < 9; ++s) {
            h16x8 w;
#pragma unroll
            for (int i = 0; i < 8; ++i)
                w[i] = (_Float16)W2[j * 288 + (ci0 + i) * 9 + s];
            *(h16x8*)(wf2 + (s * 64 + lane) * 8) = w;
        }
    }
}

// ---------------- vertical box of hq (fp16), fused a/b -> ab fp16 ----------------
__global__ __launch_bounds__(256) void k_vbox4_ab(const h16x4* __restrict__ hq,
                                                  h16x2* __restrict__ ab) {
    int x = blockIdx.x * 256 + threadIdx.x;
    int b = blockIdx.y;
    int y0 = blockIdx.z * SEG;
    int pbase = b * HW + x;
    f32x4 s = { 0.f, 0.f, 0.f, 0.f };
    int r0 = y0 - RAD < 0 ? 0 : y0 - RAD;
    for (int r = r0; r < y0 + RAD; ++r) {
        h16x4 v = hq[pbase + r * WW];
        s[0] += (float)v[0]; s[1] += (float)v[1]; s[2] += (float)v[2]; s[3] += (float)v[3];
    }
    for (int y = y0; y < y0 + SEG; ++y) {
        if (y + RAD < HH) {
            h16x4 v = hq[pbase + (y + RAD) * WW];
            s[0] += (float)v[0]; s[1] += (float)v[1]; s[2] += (float)v[2]; s[3] += (float)v[3];
        }
        float mI = s[0] * INV_K, mP = s[1] * INV_K, mIp = s[2] * INV_K, mII = s[3] * INV_K;
        float cov = mIp - mI * mP;
        float var = mII - mI * mI;
        float av = cov / (var + EPS);
        float bv = mP - av * mI;
        h16x2 o;
        o[0] = (_Float16)av; o[1] = (_Float16)bv;
        ab[pbase + y * WW] = o;
        if (y - RAD >= 0) {
            h16x4 v = hq[pbase + (y - RAD) * WW];
            s[0] -= (float)v[0]; s[1] -= (float)v[1]; s[2] -= (float)v[2]; s[3] -= (float)v[3];
        }
    }
}

// ---------------- horizontal box of ab (fp16 in/out) ----------------
__global__ __launch_bounds__(256) void k_hbox2(const h16x2* __restrict__ ab,
                                               h16x2* __restrict__ hab) {
    __shared__ float sa[WW], sb[WW];
    int base = blockIdx.x * WW;
    int tid = threadIdx.x;
    for (int x = tid; x < WW; x += 256) {
        h16x2 v = ab[base + x];
        sa[x] = (float)v[0]; sb[x] = (float)v[1];
    }
    __syncthreads();
    for (int x = tid; x < WW; x += 256) {
        float s0 = 0.f, s1 = 0.f;
        int lo = x - RAD < 0 ? 0 : x - RAD;
        int hi = x + RAD >= WW ? WW - 1 : x + RAD;
        for (int i = lo; i <= hi; ++i) { s0 += sa[i]; s1 += sb[i]; }
        h16x2 o;
        o[0] = (_Float16)(s0 * INV_K); o[1] = (_Float16)(s1 * INV_K);
        hab[base + x] = o;
    }
}

// ------- vertical box of hab (fp16) + t_guided -> feats ch4-7 (tg in ch4) -------
__global__ __launch_bounds__(256) void k_vbox2_tg(const h16x2* __restrict__ hab,
                                                  const float* __restrict__ g,
                                                  const float* __restrict__ A,
                                                  _Float16* __restrict__ feats) {
    int x = blockIdx.x * 256 + threadIdx.x;
    int b = blockIdx.y;
    int y0 = blockIdx.z * SEG;
    int pbase = b * HW + x;
    _Float16 A0 = (_Float16)A[b * 3 + 0], A1 = (_Float16)A[b * 3 + 1], A2 = (_Float16)A[b * 3 + 2];
    f32x2 s = { 0.f, 0.f };
    int r0 = y0 - RAD < 0 ? 0 : y0 - RAD;
    for (int r = r0; r < y0 + RAD; ++r) {
        h16x2 v = hab[pbase + r * WW];
        s[0] += (float)v[0]; s[1] += (float)v[1];
    }
    for (int y = y0; y < y0 + SEG; ++y) {
        if (y + RAD < HH) {
            h16x2 v = hab[pbase + (y + RAD) * WW];
            s[0] += (float)v[0]; s[1] += (float)v[1];
        }
        int o = pbase + y * WW;
        float val = (s[0] * INV_K) * g[o] + (s[1] * INV_K);
        h16x4 fv;
        fv[0] = (_Float16)val; fv[1] = A0; fv[2] = A1; fv[3] = A2;
        *(h16x4*)(feats + (size_t)o * 8 + 4) = fv;
        if (y - RAD >= 0) {
            h16x2 v = hab[pbase + (y - RAD) * WW];
            s[0] -= (float)v[0]; s[1] -= (float)v[1];
        }
    }
}

// ---------------- fused conv1+conv2+conv3, single barrier per row ----------------
// h1 LDS row: [NPX px][32 ch] fp16; 16B granule c (=ch/8) at sp = c ^ ((lp>>1)&3)
static __device__ inline h16x8 ld_h1(const _Float16* hrow, int lp, int c) {
    int sp = c ^ ((lp >> 1) & 3);
    return *(const h16x8*)(hrow + lp * 32 + sp * 8);
}
static __device__ inline void st_h1(_Float16* hrow, int lp, int u, h16x4 o) {   // u = ch/4
    int sp = (u >> 1) ^ ((lp >> 1) & 3);
    *(h16x4*)(hrow + lp * 32 + sp * 8 + (u & 1) * 4) = o;
}
// h2 LDS row: [NPX px][16 ch] fp16; granule c at sp = c ^ ((lp>>2)&1)
static __device__ inline void st_h2(_Float16* hrow, int lp, int u, h16x4 o) {   // u = ch/4
    int sp = (u >> 1) ^ ((lp >> 2) & 1);
    *(h16x4*)(hrow + lp * 16 + sp * 8 + (u & 1) * 4) = o;
}

static __device__ inline void load_b1(const _Float16* fb, int r1, int X0, int g,
                                      int j, int gq, h16x8 Bg[3]) {
    const h16x8 z = {0,0,0,0,0,0,0,0};
    bool xedgeG = (X0 == 0 && g == 0) || (X0 == 256 && g == 16);
    int gxb = X0 + XOFF + g * 16 + j;
    if (!xedgeG && r1 >= 1 && r1 <= 509) {
#pragma unroll
        for (int t = 0; t < 3; ++t) {
            int s = t * 4 + gq;
            int dy = s / 3 - 1, dx = s - (s / 3) * 3 - 1;
            Bg[t] = *(const h16x8*)(fb + ((size_t)(r1 + dy) * WW + (gxb + dx)) * 8);
        }
    } else {
#pragma unroll
        for (int t = 0; t < 3; ++t) {
            int s = t * 4 + gq;
            int dy = s / 3 - 1, dx = s - (s / 3) * 3 - 1;
            int yy = r1 + dy, xx = gxb + dx;
            bool ok = (s < 9) && yy >= 0 && yy < HH && xx >= 0 && xx < WW;
            int yc = yy < 0 ? 0 : (yy > HH - 1 ? HH - 1 : yy);
            int xc = xx < 0 ? 0 : (xx > WW - 1 ? WW - 1 : xx);
            h16x8 v = *(const h16x8*)(fb + ((size_t)yc * WW + xc) * 8);
            Bg[t] = ok ? v : z;
        }
    }
}

__global__ __launch_bounds__(512, 2) void k_cnn_fused(const _Float16* __restrict__ feats,
                                                      const _Float16* __restrict__ wf1,
                                                      const _Float16* __restrict__ wf2,
                                                      const float* __restrict__ b1,
                                                      const float* __restrict__ b2,
                                                      const float* __restrict__ W3,
                                                      const float* __restrict__ b3,
                                                      float* __restrict__ out) {
    __shared__ _Float16 h1s[3][NPX * 32];    // 52,224 B
    __shared__ _Float16 h2s2[2][NPX * 16];   // 17,408 B (slot parity = row & 1)
    __shared__ h16x8 wf1s[6 * 64];           //  6,144 B
    __shared__ h16x2 w3s[72];
    __shared__ float sB[48];                 // b1[32], b2[16]
    __shared__ float w3bias;

    int tid = threadIdx.x;
    int lane = tid & 63, wave = tid >> 6;
    int j = lane & 15, gq = lane >> 4;
    int b = blockIdx.y;
    int X0 = (blockIdx.x & 1) * 256;
    int y0 = (blockIdx.x >> 1) * TROWS;
    const _Float16* fb = feats + (size_t)b * HW * 8;
    float* outb = out + (size_t)b * HW;

    // stage wf1 into LDS (384 x 16B), wA2 into regs
    for (int q = tid; q < 384; q += 512)
        ((i32x4*)wf1s)[q] = ((const i32x4*)wf1)[q];
    const h16x8* wf2v = (const h16x8*)wf2;
    h16x8 wA2[9];
#pragma unroll
    for (int s = 0; s < 9; ++s) wA2[s] = wf2v[s * 64 + lane];
    if (tid < 72) {
        int s = tid >> 3, u = tid & 7;
        h16x2 w;
        w[0] = (_Float16)W3[(2 * u) * 9 + s];
        w[1] = (_Float16)W3[(2 * u + 1) * 9 + s];
        w3s[tid] = w;
    } else if (tid < 104) {
        sB[tid - 72] = b1[tid - 72];
    } else if (tid < 120) {
        sB[32 + tid - 104] = b2[tid - 104];
    } else if (tid == 120) w3bias = b3[0];
    __syncthreads();

    int g0 = wave * 2;
    const h16x8 z16 = {0,0,0,0,0,0,0,0};
    h16x8 Bv[2][3];                  // conv1 B prefetch, groups {g0, g0+1}
    h16x8 Bg[3];                     // g16 conv1 B (wave 5 — conv2-scatter for g16 is wave 4)
    f32x4 cA[2] = {}, cB[2] = {}, cC[2] = {};   // conv2 scatter accs
    f32x4 gA = {}, gB = {}, gC = {};            // g16 scatter accs (wave 4)
    int c3px = tid >> 1, c3h = tid & 1;
    float accN = 0.f, accC3 = 0.f;

    for (int i = 0; i < TROWS + 6; ++i) {       // 22 iterations, 1 barrier each
        int r1 = y0 + i - 2;          // conv1 produces h1[r1]
        int rp = y0 + i - 3;          // conv2-scatter consumes h1[rp]
        int r2 = y0 + i - 4;          // h2 row completed + stored
        int R  = y0 + i - 5;          // h2 row conv3 reads (written last iter)
        bool do_h1 = (i <= TROWS + 3) && (r1 >= 0) && (r1 <= 511);
        bool do_rp = (i >= 1) && (i <= TROWS + 4) && (rp >= 0) && (rp <= 511);
        bool st_r2 = (i <= TROWS + 4) && (r2 >= 0) && (r2 <= 511);
        bool rd_R  = (R >= 0) && (R <= 511);

        // ---- A: issue conv1 global loads + tg prefetch (drain under B/C/D) ----
        if (do_h1) {
#pragma unroll
            for (int k = 0; k < 2; ++k)
                load_b1(fb, r1, X0, g0 + k, j, gq, Bv[k]);
            if (wave == 5) load_b1(fb, r1, X0, 16, j, gq, Bg);
        }
        float tgv = 0.f;
        int oOut = (y0 + i - 6) * WW + X0 + c3px;
        if (i >= 6 && c3h == 0) {
            h16x4 fv = *(const h16x4*)(fb + (size_t)oOut * 8 + 4);
            tgv = (float)fv[0];
        }

        // ---- B: conv2 scatter — read h1[rp] once, update 3 row-accs ----
        f32x4 bias2v = *(const f32x4*)(sB + 32 + gq * 4);
#pragma unroll
        for (int k = 0; k < 2; ++k) {
            cA[k] = cB[k]; cB[k] = cC[k]; cC[k] = bias2v;
        }
        if (wave == 4) { gA = gB; gB = gC; gC = bias2v; }
        if (do_rp) {
            const _Float16* hrow = h1s[s3(rp)];
            __builtin_amdgcn_s_setprio(1);
#pragma unroll
            for (int k = 0; k < 2; ++k) {
                int lpb = (g0 + k) * 16 + j;
#pragma unroll
                for (int dx = 0; dx < 3; ++dx) {
                    int lpx = lpb + dx - 1;
                    h16x8 v;
                    if (wave == 0 && k == 0) {
                        int lpc = lpx < 0 ? 0 : lpx;
                        v = ld_h1(hrow, lpc, gq);
                        if (X0 == 0) v = (lpx >= 8) ? v : z16;   // src x >= 0
                    } else {
                        v = ld_h1(hrow, lpx, gq);
                    }
                    cC[k] = __builtin_amdgcn_mfma_f32_16x16x32_f16(wA2[0 + dx], v, cC[k], 0, 0, 0);
                    cB[k] = __builtin_amdgcn_mfma_f32_16x16x32_f16(wA2[3 + dx], v, cB[k], 0, 0, 0);
                    cA[k] = __builtin_amdgcn_mfma_f32_16x16x32_f16(wA2[6 + dx], v, cA[k], 0, 0, 0);
                }
            }
            if (wave == 4) {                      // group 16 scatter
                int lpb = 256 + j;
#pragma unroll
                for (int dx = 0; dx < 3; ++dx) {
                    int lpx = lpb + dx - 1;       // 255..272
                    int lpc = lpx > NPX - 1 ? NPX - 1 : lpx;
                    h16x8 v = ld_h1(hrow, lpc, gq);
                    if (X0 == 256 && lpx > 263) v = z16;   // src x < WW
                    gC = __builtin_amdgcn_mfma_f32_16x16x32_f16(wA2[0 + dx], v, gC, 0, 0, 0);
                    gB = __builtin_amdgcn_mfma_f32_16x16x32_f16(wA2[3 + dx], v, gB, 0, 0, 0);
                    gA = __builtin_amdgcn_mfma_f32_16x16x32_f16(wA2[6 + dx], v, gA, 0, 0, 0);
                }
            }
            __builtin_amdgcn_s_setprio(0);
        }

        // ---- C: store completed h2 row r2 (slot r2&1; conv3 reads slot R&1) ----
        if (st_r2) {
            _Float16* h2row = h2s2[r2 & 1];
#pragma unroll
            for (int k = 0; k < 2; ++k) {
                h16x4 o;
#pragma unroll
                for (int r = 0; r < 4; ++r) o[r] = (_Float16)fmaxf(cA[k][r], 0.f);
                st_h2(h2row, (g0 + k) * 16 + j, gq, o);
            }
            if (wave == 4) {
                h16x4 o;
#pragma unroll
                for (int r = 0; r < 4; ++r) o[r] = (_Float16)fmaxf(gA[r], 0.f);
                st_h2(h2row, 256 + j, gq, o);
            }
        }

        // ---- D: conv3 running-partials on h2 row R (written last iter) ----
        {
            float d0 = 0.f, d1 = 0.f, d2 = 0.f;
            if (rd_R) {
                const _Float16* hrow = h2s2[R & 1];
#pragma unroll
                for (int dx = 0; dx < 3; ++dx) {
                    int xim = X0 + c3px + dx - 1;
                    if (xim >= 0 && xim < WW) {
                        int lpx = c3px + 8 + dx - 1;
                        int sp = c3h ^ ((lpx >> 2) & 1);
                        h16x8 v = *(const h16x8*)(hrow + lpx * 16 + sp * 8);
#pragma unroll
                        for (int q = 0; q < 4; ++q) {
                            h16x2 pv = { v[2 * q], v[2 * q + 1] };
                            d0 = __builtin_amdgcn_fdot2(pv, w3s[(0 + dx) * 8 + 4 * c3h + q], d0, false);
                            d1 = __builtin_amdgcn_fdot2(pv, w3s[(3 + dx) * 8 + 4 * c3h + q], d1, false);
                            d2 = __builtin_amdgcn_fdot2(pv, w3s[(6 + dx) * 8 + 4 * c3h + q], d2, false);
                        }
                    }
                }
            }
            if (i >= 6) {
                float accv = accC3 + d2;
                float full = accv + __shfl_xor(accv, 1) + w3bias;
                if (c3h == 0) {
                    float sg = 1.f / (1.f + expf(-full));
                    float tf = 0.7f * tgv + 0.3f * sg;
                    outb[oOut] = fminf(fmaxf(tf, 0.f), 1.f);
                }
            }
            accC3 = accN + d1;
            accN = d0;
        }

        // ---- E: conv1 MFMA (Bv drained) + store h1 row r1 ----
        if (do_h1) {
            h16x8 w1[2][3];
#pragma unroll
            for (int cg = 0; cg < 2; ++cg)
#pragma unroll
                for (int t = 0; t < 3; ++t) w1[cg][t] = wf1s[(cg * 3 + t) * 64 + lane];
            _Float16* h1row = h1s[s3(r1)];
            f32x4 b1lo = *(const f32x4*)(sB + gq * 4);
            f32x4 b1hi = *(const f32x4*)(sB + 16 + gq * 4);
            __builtin_amdgcn_s_setprio(1);
#pragma unroll
            for (int k = 0; k < 2; ++k) {
                f32x4 a1[2] = { b1lo, b1hi };
#pragma unroll
                for (int t = 0; t < 3; ++t)
#pragma unroll
                    for (int cg = 0; cg < 2; ++cg)
                        a1[cg] = __builtin_amdgcn_mfma_f32_16x16x32_f16(w1[cg][t], Bv[k][t], a1[cg], 0, 0, 0);
                int lp = (g0 + k) * 16 + j;
#pragma unroll
                for (int cg = 0; cg < 2; ++cg) {
                    h16x4 o;
#pragma unroll
                    for (int r = 0; r < 4; ++r) o[r] = (_Float16)fmaxf(a1[cg][r], 0.f);
                    st_h1(h1row, lp, cg * 4 + gq, o);
                }
            }
            if (wave == 5) {                      // g16 conv1 (off wave 4)
                f32x4 a1[2] = { b1lo, b1hi };
#pragma unroll
                for (int t = 0; t < 3; ++t)
#pragma unroll
                    for (int cg = 0; cg < 2; ++cg)
                        a1[cg] = __builtin_amdgcn_mfma_f32_16x16x32_f16(w1[cg][t], Bg[t], a1[cg], 0, 0, 0);
                int lp = 256 + j;
#pragma unroll
                for (int cg = 0; cg < 2; ++cg) {
                    h16x4 o;
#pragma unroll
                    for (int r = 0; r < 4; ++r) o[r] = (_Float16)fmaxf(a1[cg][r], 0.f);
                    st_h1(h1row, lp, cg * 4 + gq, o);
                }
            }
            __builtin_amdgcn_s_setprio(0);
        }
        __syncthreads();
    }
}

extern "C" void kernel_launch(void* const* d_in, const int* in_sizes, int n_in,
                              void* d_out, int out_size, void* d_ws, size_t ws_size,
                              hipStream_t stream) {
    const float* I    = (const float*)d_in[0];
    const float* t0   = (const float*)d_in[1];
    const float* dark = (const float*)d_in[2];
    const float* A    = (const float*)d_in[3];
    const float* W1   = (const float*)d_in[4];
    const float* b1   = (const float*)d_in[5];
    const float* W2   = (const float*)d_in[6];
    const float* b2   = (const float*)d_in[7];
    const float* W3   = (const float*)d_in[8];
    const float* b3   = (const float*)d_in[9];
    float* out = (float*)d_out;
    float* ws  = (float*)d_ws;

    const size_t P = (size_t)BB * HW;       // 2M floats = 8 MB
    _Float16* feats = (_Float16*)(ws + P);      // [P,5P)   fp16 [B][HW][8]
    float* g        = ws + 5 * P;               // [5P,6P)  fp32
    h16x4* hq       = (h16x4*)(ws + 6 * P);     // [6P,8P)  8B/px
    h16x2* ab       = (h16x2*)(ws + 8 * P);     // [8P,9P)  4B/px
    h16x2* hab      = (h16x2*)(ws + 9 * P);     // [9P,10P) 4B/px
    _Float16* wf1   = (_Float16*)(ws + 10 * P); // 3072 halves
    _Float16* wf2   = wf1 + 6 * 64 * 8;         // 4608 halves

    k_gray_hbox4<<<BB * HH, 256, 0, stream>>>(I, t0, dark, g, hq, feats, W1, W2, wf1, wf2);
    dim3 gv(WW / 256, BB, HH / SEG);
    k_vbox4_ab<<<gv, 256, 0, stream>>>(hq, ab);
    k_hbox2<<<BB * HH, 256, 0, stream>>>(ab, hab);
    k_vbox2_tg<<<gv, 256, 0, stream>>>(hab, g, A, feats);

    dim3 gf(64, BB);                        // 32 y-tiles x 2 x-halves x 8 batches
    k_cnn_fused<<<gf, 512, 0, stream>>>(feats, wf1, wf2, b1, b2, W3, b3, out);
}

// Round 21
// 170.854 us; speedup vs baseline: 1.1347x; 1.0399x over previous
//
#include <hip/hip_runtime.h>
#include <cmath>

#define BB 8
#define HH 512
#define WW 512
#define HW (HH*WW)
#define RAD 15
#define SEG 8
#define EPS 0.001f
#define INV_K (1.0f/31.0f)
#define TROWS 16
#define NPX 272            // computed px per block: 256 out + 16 halo
#define XOFF (-8)

typedef _Float16 h16x8 __attribute__((ext_vector_type(8)));
typedef _Float16 h16x4 __attribute__((ext_vector_type(4)));
typedef _Float16 h16x2 __attribute__((ext_vector_type(2)));
typedef float f32x4 __attribute__((ext_vector_type(4)));
typedef float f32x2 __attribute__((ext_vector_type(2)));
typedef int   i32x4 __attribute__((ext_vector_type(4)));

static __device__ inline int s3(int r) { return (r + 6) % 3; }   // r >= -6

// feats channel order: {I0, I1, I2, dark | tg, A0, A1, A2} -> W1 cmap {0,1,2,4,3,5,6,7}

// ------- gray + horizontal box (fp16 hq) + feats ch0-3; block 0 packs weights -------
__global__ __launch_bounds__(256) void k_gray_hbox4(const float* __restrict__ I,
                                                    const float* __restrict__ p,
                                                    const float* __restrict__ dark,
                                                    float* __restrict__ g,
                                                    h16x4* __restrict__ hq,
                                                    _Float16* __restrict__ feats,
                                                    const float* __restrict__ W1,
                                                    const float* __restrict__ W2,
                                                    _Float16* __restrict__ wf1,
                                                    _Float16* __restrict__ wf2) {
    __shared__ float sg[WW], sp[WW];
    int row = blockIdx.x;            // b*HH + y
    int b = row >> 9;
    int base = row * WW;
    const float* Ib = I + (size_t)b * 3 * HW + (size_t)(row & 511) * WW;
    const float* db = dark + (size_t)base;
    int tid = threadIdx.x;
    for (int x = tid; x < WW; x += 256) {
        float i0 = Ib[x], i1 = Ib[HW + x], i2 = Ib[2 * HW + x];
        float gv = 0.299f * i0 + 0.587f * i1 + 0.114f * i2;
        sg[x] = gv; sp[x] = p[base + x];
        g[base + x] = gv;
        h16x4 v;
        v[0] = (_Float16)i0; v[1] = (_Float16)i1; v[2] = (_Float16)i2;
        v[3] = (_Float16)db[x];
        *(h16x4*)(feats + ((size_t)base + x) * 8) = v;
    }
    __syncthreads();
    for (int x = tid; x < WW; x += 256) {
        float s0 = 0.f, s1 = 0.f, s2 = 0.f, s3v = 0.f;
        int lo = x - RAD < 0 ? 0 : x - RAD;
        int hi = x + RAD >= WW ? WW - 1 : x + RAD;
        for (int i = lo; i <= hi; ++i) {
            float gv = sg[i], pv = sp[i];
            s0 += gv; s1 += pv; s2 += gv * pv; s3v += gv * gv;
        }
        h16x4 o;
        o[0] = (_Float16)(s0 * INV_K); o[1] = (_Float16)(s1 * INV_K);
        o[2] = (_Float16)(s2 * INV_K); o[3] = (_Float16)(s3v * INV_K);
        hq[base + x] = o;
    }
    // ---- weight fragment prepack (block 0, first wave) ----
    if (blockIdx.x == 0 && tid < 64) {
        int lane = tid;
        int j = lane & 15, gg = lane >> 4;
        const int cmap[8] = {0, 1, 2, 4, 3, 5, 6, 7};
#pragma unroll
        for (int cg = 0; cg < 2; ++cg)
#pragma unroll
            for (int t = 0; t < 3; ++t) {
                int s = t * 4 + gg;
                h16x8 w;
#pragma unroll
                for (int i = 0; i < 8; ++i)
                    w[i] = (s < 9) ? (_Float16)W1[(cg * 16 + j) * 72 + cmap[i] * 9 + s]
                                   : (_Float16)0.f;
                *(h16x8*)(wf1 + ((cg * 3 + t) * 64 + lane) * 8) = w;
            }
        int ci0 = gg * 8;
#pragma unroll
        for (int s = 0; s < 9; ++s) {
            h16x8 w;
#pragma unroll
            for (int i = 0; i < 8; ++i)
                w[i] = (_Float16)W2[j * 288 + (ci0 + i) * 9 + s];
            *(h16x8*)(wf2 + (s * 64 + lane) * 8) = w;
        }
    }
}

// ---------------- vertical box of hq (fp16), fused a/b -> ab fp16 ----------------
__global__ __launch_bounds__(256) void k_vbox4_ab(const h16x4* __restrict__ hq,
                                                  h16x2* __restrict__ ab) {
    int x = blockIdx.x * 256 + threadIdx.x;
    int b = blockIdx.y;
    int y0 = blockIdx.z * SEG;
    int pbase = b * HW + x;
    f32x4 s = { 0.f, 0.f, 0.f, 0.f };
    int r0 = y0 - RAD < 0 ? 0 : y0 - RAD;
    int rhi = (y0 + RAD > HH) ? HH : (y0 + RAD);     // clamp: rows >= HH never in any window
    for (int r = r0; r < rhi; ++r) {
        h16x4 v = hq[pbase + r * WW];
        s[0] += (float)v[0]; s[1] += (float)v[1]; s[2] += (float)v[2]; s[3] += (float)v[3];
    }
    for (int y = y0; y < y0 + SEG; ++y) {
        if (y + RAD < HH) {
            h16x4 v = hq[pbase + (y + RAD) * WW];
            s[0] += (float)v[0]; s[1] += (float)v[1]; s[2] += (float)v[2]; s[3] += (float)v[3];
        }
        float mI = s[0] * INV_K, mP = s[1] * INV_K, mIp = s[2] * INV_K, mII = s[3] * INV_K;
        float cov = mIp - mI * mP;
        float var = mII - mI * mI;
        float av = cov / (var + EPS);
        float bv = mP - av * mI;
        h16x2 o;
        o[0] = (_Float16)av; o[1] = (_Float16)bv;
        ab[pbase + y * WW] = o;
        if (y - RAD >= 0) {
            h16x4 v = hq[pbase + (y - RAD) * WW];
            s[0] -= (float)v[0]; s[1] -= (float)v[1]; s[2] -= (float)v[2]; s[3] -= (float)v[3];
        }
    }
}

// ---------------- horizontal box of ab (fp16 in/out) ----------------
__global__ __launch_bounds__(256) void k_hbox2(const h16x2* __restrict__ ab,
                                               h16x2* __restrict__ hab) {
    __shared__ float sa[WW], sb[WW];
    int base = blockIdx.x * WW;
    int tid = threadIdx.x;
    for (int x = tid; x < WW; x += 256) {
        h16x2 v = ab[base + x];
        sa[x] = (float)v[0]; sb[x] = (float)v[1];
    }
    __syncthreads();
    for (int x = tid; x < WW; x += 256) {
        float s0 = 0.f, s1 = 0.f;
        int lo = x - RAD < 0 ? 0 : x - RAD;
        int hi = x + RAD >= WW ? WW - 1 : x + RAD;
        for (int i = lo; i <= hi; ++i) { s0 += sa[i]; s1 += sb[i]; }
        h16x2 o;
        o[0] = (_Float16)(s0 * INV_K); o[1] = (_Float16)(s1 * INV_K);
        hab[base + x] = o;
    }
}

// ------- vertical box of hab (fp16) + t_guided -> feats ch4-7 (tg in ch4) -------
__global__ __launch_bounds__(256) void k_vbox2_tg(const h16x2* __restrict__ hab,
                                                  const float* __restrict__ g,
                                                  const float* __restrict__ A,
                                                  _Float16* __restrict__ feats) {
    int x = blockIdx.x * 256 + threadIdx.x;
    int b = blockIdx.y;
    int y0 = blockIdx.z * SEG;
    int pbase = b * HW + x;
    _Float16 A0 = (_Float16)A[b * 3 + 0], A1 = (_Float16)A[b * 3 + 1], A2 = (_Float16)A[b * 3 + 2];
    f32x2 s = { 0.f, 0.f };
    int r0 = y0 - RAD < 0 ? 0 : y0 - RAD;
    int rhi = (y0 + RAD > HH) ? HH : (y0 + RAD);     // clamp (see k_vbox4_ab)
    for (int r = r0; r < rhi; ++r) {
        h16x2 v = hab[pbase + r * WW];
        s[0] += (float)v[0]; s[1] += (float)v[1];
    }
    for (int y = y0; y < y0 + SEG; ++y) {
        if (y + RAD < HH) {
            h16x2 v = hab[pbase + (y + RAD) * WW];
            s[0] += (float)v[0]; s[1] += (float)v[1];
        }
        int o = pbase + y * WW;
        float val = (s[0] * INV_K) * g[o] + (s[1] * INV_K);
        h16x4 fv;
        fv[0] = (_Float16)val; fv[1] = A0; fv[2] = A1; fv[3] = A2;
        *(h16x4*)(feats + (size_t)o * 8 + 4) = fv;
        if (y - RAD >= 0) {
            h16x2 v = hab[pbase + (y - RAD) * WW];
            s[0] -= (float)v[0]; s[1] -= (float)v[1];
        }
    }
}

// ---------------- fused conv1+conv2+conv3, single barrier per row ----------------
// h1 LDS row: [NPX px][32 ch] fp16; 16B granule c (=ch/8) at sp = c ^ ((lp>>1)&3)
static __device__ inline h16x8 ld_h1(const _Float16* hrow, int lp, int c) {
    int sp = c ^ ((lp >> 1) & 3);
    return *(const h16x8*)(hrow + lp * 32 + sp * 8);
}
static __device__ inline void st_h1(_Float16* hrow, int lp, int u, h16x4 o) {   // u = ch/4
    int sp = (u >> 1) ^ ((lp >> 1) & 3);
    *(h16x4*)(hrow + lp * 32 + sp * 8 + (u & 1) * 4) = o;
}
// h2 LDS row: [NPX px][16 ch] fp16; granule c at sp = c ^ ((lp>>2)&1)
static __device__ inline void st_h2(_Float16* hrow, int lp, int u, h16x4 o) {   // u = ch/4
    int sp = (u >> 1) ^ ((lp >> 2) & 1);
    *(h16x4*)(hrow + lp * 16 + sp * 8 + (u & 1) * 4) = o;
}

static __device__ inline void load_b1(const _Float16* fb, int r1, int X0, int g,
                                      int j, int gq, h16x8 Bg[3]) {
    const h16x8 z = {0,0,0,0,0,0,0,0};
    bool xedgeG = (X0 == 0 && g == 0) || (X0 == 256 && g == 16);
    int gxb = X0 + XOFF + g * 16 + j;
    if (!xedgeG && r1 >= 1 && r1 <= 509) {
#pragma unroll
        for (int t = 0; t < 3; ++t) {
            int s = t * 4 + gq;
            int dy = s / 3 - 1, dx = s - (s / 3) * 3 - 1;
            Bg[t] = *(const h16x8*)(fb + ((size_t)(r1 + dy) * WW + (gxb + dx)) * 8);
        }
    } else {
#pragma unroll
        for (int t = 0; t < 3; ++t) {
            int s = t * 4 + gq;
            int dy = s / 3 - 1, dx = s - (s / 3) * 3 - 1;
            int yy = r1 + dy, xx = gxb + dx;
            bool ok = (s < 9) && yy >= 0 && yy < HH && xx >= 0 && xx < WW;
            int yc = yy < 0 ? 0 : (yy > HH - 1 ? HH - 1 : yy);
            int xc = xx < 0 ? 0 : (xx > WW - 1 ? WW - 1 : xx);
            h16x8 v = *(const h16x8*)(fb + ((size_t)yc * WW + xc) * 8);
            Bg[t] = ok ? v : z;
        }
    }
}

__global__ __launch_bounds__(512, 2) void k_cnn_fused(const _Float16* __restrict__ feats,
                                                      const _Float16* __restrict__ wf1,
                                                      const _Float16* __restrict__ wf2,
                                                      const float* __restrict__ b1,
                                                      const float* __restrict__ b2,
                                                      const float* __restrict__ W3,
                                                      const float* __restrict__ b3,
                                                      float* __restrict__ out) {
    __shared__ _Float16 h1s[3][NPX * 32];    // 52,224 B
    __shared__ _Float16 h2s2[2][NPX * 16];   // 17,408 B (slot parity = row & 1)
    __shared__ h16x8 wf1s[6 * 64];           //  6,144 B
    __shared__ h16x2 w3s[72];
    __shared__ float sB[48];                 // b1[32], b2[16]
    __shared__ float w3bias;

    int tid = threadIdx.x;
    int lane = tid & 63, wave = tid >> 6;
    int j = lane & 15, gq = lane >> 4;
    int b = blockIdx.y;
    int X0 = (blockIdx.x & 1) * 256;
    int y0 = (blockIdx.x >> 1) * TROWS;
    const _Float16* fb = feats + (size_t)b * HW * 8;
    float* outb = out + (size_t)b * HW;

    // stage wf1 into LDS (384 x 16B), wA2 into regs
    for (int q = tid; q < 384; q += 512)
        ((i32x4*)wf1s)[q] = ((const i32x4*)wf1)[q];
    const h16x8* wf2v = (const h16x8*)wf2;
    h16x8 wA2[9];
#pragma unroll
    for (int s = 0; s < 9; ++s) wA2[s] = wf2v[s * 64 + lane];
    if (tid < 72) {
        int s = tid >> 3, u = tid & 7;
        h16x2 w;
        w[0] = (_Float16)W3[(2 * u) * 9 + s];
        w[1] = (_Float16)W3[(2 * u + 1) * 9 + s];
        w3s[tid] = w;
    } else if (tid < 104) {
        sB[tid - 72] = b1[tid - 72];
    } else if (tid < 120) {
        sB[32 + tid - 104] = b2[tid - 104];
    } else if (tid == 120) w3bias = b3[0];
    __syncthreads();

    int g0 = wave * 2;
    const h16x8 z16 = {0,0,0,0,0,0,0,0};
    h16x8 Bv[2][3];                  // conv1 B prefetch, groups {g0, g0+1}
    h16x8 Bg[3];                     // g16 conv1 B (wave 5 — conv2-scatter for g16 is wave 4)
    f32x4 cA[2] = {}, cB[2] = {}, cC[2] = {};   // conv2 scatter accs
    f32x4 gA = {}, gB = {}, gC = {};            // g16 scatter accs (wave 4)
    int c3px = tid >> 1, c3h = tid & 1;
    float accN = 0.f, accC3 = 0.f;

    for (int i = 0; i < TROWS + 6; ++i) {       // 22 iterations, 1 barrier each
        int r1 = y0 + i - 2;          // conv1 produces h1[r1]
        int rp = y0 + i - 3;          // conv2-scatter consumes h1[rp]
        int r2 = y0 + i - 4;          // h2 row completed + stored
        int R  = y0 + i - 5;          // h2 row conv3 reads (written last iter)
        bool do_h1 = (i <= TROWS + 3) && (r1 >= 0) && (r1 <= 511);
        bool do_rp = (i >= 1) && (i <= TROWS + 4) && (rp >= 0) && (rp <= 511);
        bool st_r2 = (i <= TROWS + 4) && (r2 >= 0) && (r2 <= 511);
        bool rd_R  = (R >= 0) && (R <= 511);

        // ---- A: issue conv1 global loads + tg prefetch (drain under B/C/D) ----
        if (do_h1) {
#pragma unroll
            for (int k = 0; k < 2; ++k)
                load_b1(fb, r1, X0, g0 + k, j, gq, Bv[k]);
            if (wave == 5) load_b1(fb, r1, X0, 16, j, gq, Bg);
        }
        float tgv = 0.f;
        int oOut = (y0 + i - 6) * WW + X0 + c3px;
        if (i >= 6 && c3h == 0) {
            h16x4 fv = *(const h16x4*)(fb + (size_t)oOut * 8 + 4);
            tgv = (float)fv[0];
        }

        // ---- B: conv2 scatter — read h1[rp] once, update 3 row-accs ----
        f32x4 bias2v = *(const f32x4*)(sB + 32 + gq * 4);
#pragma unroll
        for (int k = 0; k < 2; ++k) {
            cA[k] = cB[k]; cB[k] = cC[k]; cC[k] = bias2v;
        }
        if (wave == 4) { gA = gB; gB = gC; gC = bias2v; }
        if (do_rp) {
            const _Float16* hrow = h1s[s3(rp)];
            __builtin_amdgcn_s_setprio(1);
#pragma unroll
            for (int k = 0; k < 2; ++k) {
                int lpb = (g0 + k) * 16 + j;
#pragma unroll
                for (int dx = 0; dx < 3; ++dx) {
                    int lpx = lpb + dx - 1;
                    h16x8 v;
                    if (wave == 0 && k == 0) {
                        int lpc = lpx < 0 ? 0 : lpx;
                        v = ld_h1(hrow, lpc, gq);
                        if (X0 == 0) v = (lpx >= 8) ? v : z16;   // src x >= 0
                    } else {
                        v = ld_h1(hrow, lpx, gq);
                    }
                    cC[k] = __builtin_amdgcn_mfma_f32_16x16x32_f16(wA2[0 + dx], v, cC[k], 0, 0, 0);
                    cB[k] = __builtin_amdgcn_mfma_f32_16x16x32_f16(wA2[3 + dx], v, cB[k], 0, 0, 0);
                    cA[k] = __builtin_amdgcn_mfma_f32_16x16x32_f16(wA2[6 + dx], v, cA[k], 0, 0, 0);
                }
            }
            if (wave == 4) {                      // group 16 scatter
                int lpb = 256 + j;
#pragma unroll
                for (int dx = 0; dx < 3; ++dx) {
                    int lpx = lpb + dx - 1;       // 255..272
                    int lpc = lpx > NPX - 1 ? NPX - 1 : lpx;
                    h16x8 v = ld_h1(hrow, lpc, gq);
                    if (X0 == 256 && lpx > 263) v = z16;   // src x < WW
                    gC = __builtin_amdgcn_mfma_f32_16x16x32_f16(wA2[0 + dx], v, gC, 0, 0, 0);
                    gB = __builtin_amdgcn_mfma_f32_16x16x32_f16(wA2[3 + dx], v, gB, 0, 0, 0);
                    gA = __builtin_amdgcn_mfma_f32_16x16x32_f16(wA2[6 + dx], v, gA, 0, 0, 0);
                }
            }
            __builtin_amdgcn_s_setprio(0);
        }

        // ---- C: store completed h2 row r2 (slot r2&1; conv3 reads slot R&1) ----
        if (st_r2) {
            _Float16* h2row = h2s2[r2 & 1];
#pragma unroll
            for (int k = 0; k < 2; ++k) {
                h16x4 o;
#pragma unroll
                for (int r = 0; r < 4; ++r) o[r] = (_Float16)fmaxf(cA[k][r], 0.f);
                st_h2(h2row, (g0 + k) * 16 + j, gq, o);
            }
            if (wave == 4) {
                h16x4 o;
#pragma unroll
                for (int r = 0; r < 4; ++r) o[r] = (_Float16)fmaxf(gA[r], 0.f);
                st_h2(h2row, 256 + j, gq, o);
            }
        }

        // ---- D: conv3 running-partials on h2 row R (written last iter) ----
        {
            float d0 = 0.f, d1 = 0.f, d2 = 0.f;
            if (rd_R) {
                const _Float16* hrow = h2s2[R & 1];
#pragma unroll
                for (int dx = 0; dx < 3; ++dx) {
                    int xim = X0 + c3px + dx - 1;
                    if (xim >= 0 && xim < WW) {
                        int lpx = c3px + 8 + dx - 1;
                        int sp = c3h ^ ((lpx >> 2) & 1);
                        h16x8 v = *(const h16x8*)(hrow + lpx * 16 + sp * 8);
#pragma unroll
                        for (int q = 0; q < 4; ++q) {
                            h16x2 pv = { v[2 * q], v[2 * q + 1] };
                            d0 = __builtin_amdgcn_fdot2(pv, w3s[(0 + dx) * 8 + 4 * c3h + q], d0, false);
                            d1 = __builtin_amdgcn_fdot2(pv, w3s[(3 + dx) * 8 + 4 * c3h + q], d1, false);
                            d2 = __builtin_amdgcn_fdot2(pv, w3s[(6 + dx) * 8 + 4 * c3h + q], d2, false);
                        }
                    }
                }
            }
            if (i >= 6) {
                float accv = accC3 + d2;
                float full = accv + __shfl_xor(accv, 1) + w3bias;
                if (c3h == 0) {
                    float sg = 1.f / (1.f + expf(-full));
                    float tf = 0.7f * tgv + 0.3f * sg;
                    outb[oOut] = fminf(fmaxf(tf, 0.f), 1.f);
                }
            }
            accC3 = accN + d1;
            accN = d0;
        }

        // ---- E: conv1 MFMA (Bv drained) + store h1 row r1 ----
        if (do_h1) {
            h16x8 w1[2][3];
#pragma unroll
            for (int cg = 0; cg < 2; ++cg)
#pragma unroll
                for (int t = 0; t < 3; ++t) w1[cg][t] = wf1s[(cg * 3 + t) * 64 + lane];
            _Float16* h1row = h1s[s3(r1)];
            f32x4 b1lo = *(const f32x4*)(sB + gq * 4);
            f32x4 b1hi = *(const f32x4*)(sB + 16 + gq * 4);
            __builtin_amdgcn_s_setprio(1);
#pragma unroll
            for (int k = 0; k < 2; ++k) {
                f32x4 a1[2] = { b1lo, b1hi };
#pragma unroll
                for (int t = 0; t < 3; ++t)
#pragma unroll
                    for (int cg = 0; cg < 2; ++cg)
                        a1[cg] = __builtin_amdgcn_mfma_f32_16x16x32_f16(w1[cg][t], Bv[k][t], a1[cg], 0, 0, 0);
                int lp = (g0 + k) * 16 + j;
#pragma unroll
                for (int cg = 0; cg < 2; ++cg) {
                    h16x4 o;
#pragma unroll
                    for (int r = 0; r < 4; ++r) o[r] = (_Float16)fmaxf(a1[cg][r], 0.f);
                    st_h1(h1row, lp, cg * 4 + gq, o);
                }
            }
            if (wave == 5) {                      // g16 conv1 (off wave 4)
                f32x4 a1[2] = { b1lo, b1hi };
#pragma unroll
                for (int t = 0; t < 3; ++t)
#pragma unroll
                    for (int cg = 0; cg < 2; ++cg)
                        a1[cg] = __builtin_amdgcn_mfma_f32_16x16x32_f16(w1[cg][t], Bg[t], a1[cg], 0, 0, 0);
                int lp = 256 + j;
#pragma unroll
                for (int cg = 0; cg < 2; ++cg) {
                    h16x4 o;
#pragma unroll
                    for (int r = 0; r < 4; ++r) o[r] = (_Float16)fmaxf(a1[cg][r], 0.f);
                    st_h1(h1row, lp, cg * 4 + gq, o);
                }
            }
            __builtin_amdgcn_s_setprio(0);
        }
        __syncthreads();
    }
}

extern "C" void kernel_launch(void* const* d_in, const int* in_sizes, int n_in,
                              void* d_out, int out_size, void* d_ws, size_t ws_size,
                              hipStream_t stream) {
    const float* I    = (const float*)d_in[0];
    const float* t0   = (const float*)d_in[1];
    const float* dark = (const float*)d_in[2];
    const float* A    = (const float*)d_in[3];
    const float* W1   = (const float*)d_in[4];
    const float* b1   = (const float*)d_in[5];
    const float* W2   = (const float*)d_in[6];
    const float* b2   = (const float*)d_in[7];
    const float* W3   = (const float*)d_in[8];
    const float* b3   = (const float*)d_in[9];
    float* out = (float*)d_out;
    float* ws  = (float*)d_ws;

    const size_t P = (size_t)BB * HW;       // 2M floats = 8 MB
    _Float16* feats = (_Float16*)(ws + P);      // [P,5P)   fp16 [B][HW][8]
    float* g        = ws + 5 * P;               // [5P,6P)  fp32
    h16x4* hq       = (h16x4*)(ws + 6 * P);     // [6P,8P)  8B/px
    h16x2* ab       = (h16x2*)(ws + 8 * P);     // [8P,9P)  4B/px
    h16x2* hab      = (h16x2*)(ws + 9 * P);     // [9P,10P) 4B/px
    _Float16* wf1   = (_Float16*)(ws + 10 * P); // 3072 halves
    _Float16* wf2   = wf1 + 6 * 64 * 8;         // 4608 halves

    k_gray_hbox4<<<BB * HH, 256, 0, stream>>>(I, t0, dark, g, hq, feats, W1, W2, wf1, wf2);
    dim3 gv(WW / 256, BB, HH / SEG);
    k_vbox4_ab<<<gv, 256, 0, stream>>>(hq, ab);
    k_hbox2<<<BB * HH, 256, 0, stream>>>(ab, hab);
    k_vbox2_tg<<<gv, 256, 0, stream>>>(hab, g, A, feats);

    dim3 gf(64, BB);                        // 32 y-tiles x 2 x-halves x 8 batches
    k_cnn_fused<<<gf, 512, 0, stream>>>(feats, wf1, wf2, b1, b2, W3, b3, out);
}

// Round 22
// 168.854 us; speedup vs baseline: 1.1481x; 1.0118x over previous
//
#include <hip/hip_runtime.h>
#include <cmath>

#define BB 8
#define HH 512
#define WW 512
#define HW (HH*WW)
#define RAD 15
#define SEG 8
#define EPS 0.001f
#define INV_K (1.0f/31.0f)
#define TROWS 16
#define NPX 272            // computed px per block: 256 out + 16 halo
#define XOFF (-8)

typedef _Float16 h16x8 __attribute__((ext_vector_type(8)));
typedef _Float16 h16x4 __attribute__((ext_vector_type(4)));
typedef _Float16 h16x2 __attribute__((ext_vector_type(2)));
typedef float f32x4 __attribute__((ext_vector_type(4)));
typedef float f32x2 __attribute__((ext_vector_type(2)));
typedef int   i32x4 __attribute__((ext_vector_type(4)));

static __device__ inline int s3(int r) { return (r + 6) % 3; }   // r >= -6

// feats channel order: {I0, I1, I2, dark | tg, A0, A1, A2} -> W1 cmap {0,1,2,4,3,5,6,7}

// ------- gray + horizontal box (fp16 hq) + feats ch0-3; block 0 packs weights -------
__global__ __launch_bounds__(256) void k_gray_hbox4(const float* __restrict__ I,
                                                    const float* __restrict__ p,
                                                    const float* __restrict__ dark,
                                                    float* __restrict__ g,
                                                    h16x4* __restrict__ hq,
                                                    _Float16* __restrict__ feats,
                                                    const float* __restrict__ W1,
                                                    const float* __restrict__ W2,
                                                    _Float16* __restrict__ wf1,
                                                    _Float16* __restrict__ wf2) {
    __shared__ f32x2 sgp[WW];        // packed {gray, p} -> one ds_read_b64 per tap
    int row = blockIdx.x;            // b*HH + y
    int b = row >> 9;
    int base = row * WW;
    const float* Ib = I + (size_t)b * 3 * HW + (size_t)(row & 511) * WW;
    const float* db = dark + (size_t)base;
    int tid = threadIdx.x;
    for (int x = tid; x < WW; x += 256) {
        float i0 = Ib[x], i1 = Ib[HW + x], i2 = Ib[2 * HW + x];
        float gv = 0.299f * i0 + 0.587f * i1 + 0.114f * i2;
        f32x2 gp = { gv, p[base + x] };
        sgp[x] = gp;
        g[base + x] = gv;
        h16x4 v;
        v[0] = (_Float16)i0; v[1] = (_Float16)i1; v[2] = (_Float16)i2;
        v[3] = (_Float16)db[x];
        *(h16x4*)(feats + ((size_t)base + x) * 8) = v;
    }
    __syncthreads();
    for (int x = tid; x < WW; x += 256) {
        float s0 = 0.f, s1 = 0.f, s2 = 0.f, s3v = 0.f;
        int lo = x - RAD < 0 ? 0 : x - RAD;
        int hi = x + RAD >= WW ? WW - 1 : x + RAD;
        for (int i = lo; i <= hi; ++i) {
            f32x2 v = sgp[i];
            s0 += v[0]; s1 += v[1]; s2 += v[0] * v[1]; s3v += v[0] * v[0];
        }
        h16x4 o;
        o[0] = (_Float16)(s0 * INV_K); o[1] = (_Float16)(s1 * INV_K);
        o[2] = (_Float16)(s2 * INV_K); o[3] = (_Float16)(s3v * INV_K);
        hq[base + x] = o;
    }
    // ---- weight fragment prepack (block 0, first wave) ----
    if (blockIdx.x == 0 && tid < 64) {
        int lane = tid;
        int j = lane & 15, gg = lane >> 4;
        const int cmap[8] = {0, 1, 2, 4, 3, 5, 6, 7};
#pragma unroll
        for (int cg = 0; cg < 2; ++cg)
#pragma unroll
            for (int t = 0; t < 3; ++t) {
                int s = t * 4 + gg;
                h16x8 w;
#pragma unroll
                for (int i = 0; i < 8; ++i)
                    w[i] = (s < 9) ? (_Float16)W1[(cg * 16 + j) * 72 + cmap[i] * 9 + s]
                                   : (_Float16)0.f;
                *(h16x8*)(wf1 + ((cg * 3 + t) * 64 + lane) * 8) = w;
            }
        int ci0 = gg * 8;
#pragma unroll
        for (int s = 0; s < 9; ++s) {
            h16x8 w;
#pragma unroll
            for (int i = 0; i < 8; ++i)
                w[i] = (_Float16)W2[j * 288 + (ci0 + i) * 9 + s];
            *(h16x8*)(wf2 + (s * 64 + lane) * 8) = w;
        }
    }
}

// ---------------- vertical box of hq (fp16), fused a/b -> ab fp16 ----------------
__global__ __launch_bounds__(256) void k_vbox4_ab(const h16x4* __restrict__ hq,
                                                  h16x2* __restrict__ ab) {
    int x = blockIdx.x * 256 + threadIdx.x;
    int b = blockIdx.y;
    int y0 = blockIdx.z * SEG;
    int pbase = b * HW + x;
    f32x4 s = { 0.f, 0.f, 0.f, 0.f };
    int r0 = y0 - RAD < 0 ? 0 : y0 - RAD;
    int rhi = (y0 + RAD > HH) ? HH : (y0 + RAD);     // clamp: rows >= HH never in any window
    for (int r = r0; r < rhi; ++r) {
        h16x4 v = hq[pbase + r * WW];
        s[0] += (float)v[0]; s[1] += (float)v[1]; s[2] += (float)v[2]; s[3] += (float)v[3];
    }
    for (int y = y0; y < y0 + SEG; ++y) {
        if (y + RAD < HH) {
            h16x4 v = hq[pbase + (y + RAD) * WW];
            s[0] += (float)v[0]; s[1] += (float)v[1]; s[2] += (float)v[2]; s[3] += (float)v[3];
        }
        float mI = s[0] * INV_K, mP = s[1] * INV_K, mIp = s[2] * INV_K, mII = s[3] * INV_K;
        float cov = mIp - mI * mP;
        float var = mII - mI * mI;
        float av = cov / (var + EPS);
        float bv = mP - av * mI;
        h16x2 o;
        o[0] = (_Float16)av; o[1] = (_Float16)bv;
        ab[pbase + y * WW] = o;
        if (y - RAD >= 0) {
            h16x4 v = hq[pbase + (y - RAD) * WW];
            s[0] -= (float)v[0]; s[1] -= (float)v[1]; s[2] -= (float)v[2]; s[3] -= (float)v[3];
        }
    }
}

// ---------------- horizontal box of ab (fp16 in/out) ----------------
__global__ __launch_bounds__(256) void k_hbox2(const h16x2* __restrict__ ab,
                                               h16x2* __restrict__ hab) {
    __shared__ f32x2 sab[WW];        // packed {a,b} -> one ds_read_b64 per tap
    int base = blockIdx.x * WW;
    int tid = threadIdx.x;
    for (int x = tid; x < WW; x += 256) {
        h16x2 v = ab[base + x];
        f32x2 w = { (float)v[0], (float)v[1] };
        sab[x] = w;
    }
    __syncthreads();
    for (int x = tid; x < WW; x += 256) {
        float s0 = 0.f, s1 = 0.f;
        int lo = x - RAD < 0 ? 0 : x - RAD;
        int hi = x + RAD >= WW ? WW - 1 : x + RAD;
        for (int i = lo; i <= hi; ++i) {
            f32x2 v = sab[i];
            s0 += v[0]; s1 += v[1];
        }
        h16x2 o;
        o[0] = (_Float16)(s0 * INV_K); o[1] = (_Float16)(s1 * INV_K);
        hab[base + x] = o;
    }
}

// ------- vertical box of hab (fp16) + t_guided -> feats ch4-7 (tg in ch4) -------
__global__ __launch_bounds__(256) void k_vbox2_tg(const h16x2* __restrict__ hab,
                                                  const float* __restrict__ g,
                                                  const float* __restrict__ A,
                                                  _Float16* __restrict__ feats) {
    int x = blockIdx.x * 256 + threadIdx.x;
    int b = blockIdx.y;
    int y0 = blockIdx.z * SEG;
    int pbase = b * HW + x;
    _Float16 A0 = (_Float16)A[b * 3 + 0], A1 = (_Float16)A[b * 3 + 1], A2 = (_Float16)A[b * 3 + 2];
    f32x2 s = { 0.f, 0.f };
    int r0 = y0 - RAD < 0 ? 0 : y0 - RAD;
    int rhi = (y0 + RAD > HH) ? HH : (y0 + RAD);     // clamp (see k_vbox4_ab)
    for (int r = r0; r < rhi; ++r) {
        h16x2 v = hab[pbase + r * WW];
        s[0] += (float)v[0]; s[1] += (float)v[1];
    }
    for (int y = y0; y < y0 + SEG; ++y) {
        if (y + RAD < HH) {
            h16x2 v = hab[pbase + (y + RAD) * WW];
            s[0] += (float)v[0]; s[1] += (float)v[1];
        }
        int o = pbase + y * WW;
        float val = (s[0] * INV_K) * g[o] + (s[1] * INV_K);
        h16x4 fv;
        fv[0] = (_Float16)val; fv[1] = A0; fv[2] = A1; fv[3] = A2;
        *(h16x4*)(feats + (size_t)o * 8 + 4) = fv;
        if (y - RAD >= 0) {
            h16x2 v = hab[pbase + (y - RAD) * WW];
            s[0] -= (float)v[0]; s[1] -= (float)v[1];
        }
    }
}

// ---------------- fused conv1+conv2+conv3, single barrier per row ----------------
// h1 LDS row: [NPX px][32 ch] fp16; 16B granule c (=ch/8) at sp = c ^ ((lp>>1)&3)
static __device__ inline h16x8 ld_h1(const _Float16* hrow, int lp, int c) {
    int sp = c ^ ((lp >> 1) & 3);
    return *(const h16x8*)(hrow + lp * 32 + sp * 8);
}
static __device__ inline void st_h1(_Float16* hrow, int lp, int u, h16x4 o) {   // u = ch/4
    int sp = (u >> 1) ^ ((lp >> 1) & 3);
    *(h16x4*)(hrow + lp * 32 + sp * 8 + (u & 1) * 4) = o;
}
// h2 LDS row: [NPX px][16 ch] fp16; granule c at sp = c ^ ((lp>>2)&1)
static __device__ inline void st_h2(_Float16* hrow, int lp, int u, h16x4 o) {   // u = ch/4
    int sp = (u >> 1) ^ ((lp >> 2) & 1);
    *(h16x4*)(hrow + lp * 16 + sp * 8 + (u & 1) * 4) = o;
}

static __device__ inline void load_b1(const _Float16* fb, int r1, int X0, int g,
                                      int j, int gq, h16x8 Bg[3]) {
    const h16x8 z = {0,0,0,0,0,0,0,0};
    bool xedgeG = (X0 == 0 && g == 0) || (X0 == 256 && g == 16);
    int gxb = X0 + XOFF + g * 16 + j;
    if (!xedgeG && r1 >= 1 && r1 <= 509) {
#pragma unroll
        for (int t = 0; t < 3; ++t) {
            int s = t * 4 + gq;
            int dy = s / 3 - 1, dx = s - (s / 3) * 3 - 1;
            Bg[t] = *(const h16x8*)(fb + ((size_t)(r1 + dy) * WW + (gxb + dx)) * 8);
        }
    } else {
#pragma unroll
        for (int t = 0; t < 3; ++t) {
            int s = t * 4 + gq;
            int dy = s / 3 - 1, dx = s - (s / 3) * 3 - 1;
            int yy = r1 + dy, xx = gxb + dx;
            bool ok = (s < 9) && yy >= 0 && yy < HH && xx >= 0 && xx < WW;
            int yc = yy < 0 ? 0 : (yy > HH - 1 ? HH - 1 : yy);
            int xc = xx < 0 ? 0 : (xx > WW - 1 ? WW - 1 : xx);
            h16x8 v = *(const h16x8*)(fb + ((size_t)yc * WW + xc) * 8);
            Bg[t] = ok ? v : z;
        }
    }
}

__global__ __launch_bounds__(512, 2) void k_cnn_fused(const _Float16* __restrict__ feats,
                                                      const _Float16* __restrict__ wf1,
                                                      const _Float16* __restrict__ wf2,
                                                      const float* __restrict__ b1,
                                                      const float* __restrict__ b2,
                                                      const float* __restrict__ W3,
                                                      const float* __restrict__ b3,
                                                      float* __restrict__ out) {
    __shared__ _Float16 h1s[3][NPX * 32];    // 52,224 B
    __shared__ _Float16 h2s2[2][NPX * 16];   // 17,408 B (slot parity = row & 1)
    __shared__ h16x8 wf1s[6 * 64];           //  6,144 B
    __shared__ h16x2 w3s[72];
    __shared__ float sB[48];                 // b1[32], b2[16]
    __shared__ float w3bias;

    int tid = threadIdx.x;
    int lane = tid & 63, wave = tid >> 6;
    int j = lane & 15, gq = lane >> 4;
    int b = blockIdx.y;
    int X0 = (blockIdx.x & 1) * 256;
    int y0 = (blockIdx.x >> 1) * TROWS;
    const _Float16* fb = feats + (size_t)b * HW * 8;
    float* outb = out + (size_t)b * HW;

    // stage wf1 into LDS (384 x 16B), wA2 into regs
    for (int q = tid; q < 384; q += 512)
        ((i32x4*)wf1s)[q] = ((const i32x4*)wf1)[q];
    const h16x8* wf2v = (const h16x8*)wf2;
    h16x8 wA2[9];
#pragma unroll
    for (int s = 0; s < 9; ++s) wA2[s] = wf2v[s * 64 + lane];
    if (tid < 72) {
        int s = tid >> 3, u = tid & 7;
        h16x2 w;
        w[0] = (_Float16)W3[(2 * u) * 9 + s];
        w[1] = (_Float16)W3[(2 * u + 1) * 9 + s];
        w3s[tid] = w;
    } else if (tid < 104) {
        sB[tid - 72] = b1[tid - 72];
    } else if (tid < 120) {
        sB[32 + tid - 104] = b2[tid - 104];
    } else if (tid == 120) w3bias = b3[0];
    __syncthreads();

    int g0 = wave * 2;
    const h16x8 z16 = {0,0,0,0,0,0,0,0};
    h16x8 Bv[2][3];                  // conv1 B prefetch, groups {g0, g0+1}
    h16x8 Bg[3];                     // g16 conv1 B (wave 5 — conv2-scatter for g16 is wave 4)
    f32x4 cA[2] = {}, cB[2] = {}, cC[2] = {};   // conv2 scatter accs
    f32x4 gA = {}, gB = {}, gC = {};            // g16 scatter accs (wave 4)
    int c3px = tid >> 1, c3h = tid & 1;
    float accN = 0.f, accC3 = 0.f;

    for (int i = 0; i < TROWS + 6; ++i) {       // 22 iterations, 1 barrier each
        int r1 = y0 + i - 2;          // conv1 produces h1[r1]
        int rp = y0 + i - 3;          // conv2-scatter consumes h1[rp]
        int r2 = y0 + i - 4;          // h2 row completed + stored
        int R  = y0 + i - 5;          // h2 row conv3 reads (written last iter)
        bool do_h1 = (i <= TROWS + 3) && (r1 >= 0) && (r1 <= 511);
        bool do_rp = (i >= 1) && (i <= TROWS + 4) && (rp >= 0) && (rp <= 511);
        bool st_r2 = (i <= TROWS + 4) && (r2 >= 0) && (r2 <= 511);
        bool rd_R  = (R >= 0) && (R <= 511);

        // ---- A: issue conv1 global loads + tg prefetch (drain under B/C/D) ----
        if (do_h1) {
#pragma unroll
            for (int k = 0; k < 2; ++k)
                load_b1(fb, r1, X0, g0 + k, j, gq, Bv[k]);
            if (wave == 5) load_b1(fb, r1, X0, 16, j, gq, Bg);
        }
        float tgv = 0.f;
        int oOut = (y0 + i - 6) * WW + X0 + c3px;
        if (i >= 6 && c3h == 0) {
            h16x4 fv = *(const h16x4*)(fb + (size_t)oOut * 8 + 4);
            tgv = (float)fv[0];
        }

        // ---- B: conv2 scatter — read h1[rp] once, update 3 row-accs ----
        f32x4 bias2v = *(const f32x4*)(sB + 32 + gq * 4);
#pragma unroll
        for (int k = 0; k < 2; ++k) {
            cA[k] = cB[k]; cB[k] = cC[k]; cC[k] = bias2v;
        }
        if (wave == 4) { gA = gB; gB = gC; gC = bias2v; }
        if (do_rp) {
            const _Float16* hrow = h1s[s3(rp)];
            __builtin_amdgcn_s_setprio(1);
#pragma unroll
            for (int k = 0; k < 2; ++k) {
                int lpb = (g0 + k) * 16 + j;
#pragma unroll
                for (int dx = 0; dx < 3; ++dx) {
                    int lpx = lpb + dx - 1;
                    h16x8 v;
                    if (wave == 0 && k == 0) {
                        int lpc = lpx < 0 ? 0 : lpx;
                        v = ld_h1(hrow, lpc, gq);
                        if (X0 == 0) v = (lpx >= 8) ? v : z16;   // src x >= 0
                    } else {
                        v = ld_h1(hrow, lpx, gq);
                    }
                    cC[k] = __builtin_amdgcn_mfma_f32_16x16x32_f16(wA2[0 + dx], v, cC[k], 0, 0, 0);
                    cB[k] = __builtin_amdgcn_mfma_f32_16x16x32_f16(wA2[3 + dx], v, cB[k], 0, 0, 0);
                    cA[k] = __builtin_amdgcn_mfma_f32_16x16x32_f16(wA2[6 + dx], v, cA[k], 0, 0, 0);
                }
            }
            if (wave == 4) {                      // group 16 scatter
                int lpb = 256 + j;
#pragma unroll
                for (int dx = 0; dx < 3; ++dx) {
                    int lpx = lpb + dx - 1;       // 255..272
                    int lpc = lpx > NPX - 1 ? NPX - 1 : lpx;
                    h16x8 v = ld_h1(hrow, lpc, gq);
                    if (X0 == 256 && lpx > 263) v = z16;   // src x < WW
                    gC = __builtin_amdgcn_mfma_f32_16x16x32_f16(wA2[0 + dx], v, gC, 0, 0, 0);
                    gB = __builtin_amdgcn_mfma_f32_16x16x32_f16(wA2[3 + dx], v, gB, 0, 0, 0);
                    gA = __builtin_amdgcn_mfma_f32_16x16x32_f16(wA2[6 + dx], v, gA, 0, 0, 0);
                }
            }
            __builtin_amdgcn_s_setprio(0);
        }

        // ---- C: store completed h2 row r2 (slot r2&1; conv3 reads slot R&1) ----
        if (st_r2) {
            _Float16* h2row = h2s2[r2 & 1];
#pragma unroll
            for (int k = 0; k < 2; ++k) {
                h16x4 o;
#pragma unroll
                for (int r = 0; r < 4; ++r) o[r] = (_Float16)fmaxf(cA[k][r], 0.f);
                st_h2(h2row, (g0 + k) * 16 + j, gq, o);
            }
            if (wave == 4) {
                h16x4 o;
#pragma unroll
                for (int r = 0; r < 4; ++r) o[r] = (_Float16)fmaxf(gA[r], 0.f);
                st_h2(h2row, 256 + j, gq, o);
            }
        }

        // ---- D: conv3 running-partials on h2 row R (written last iter) ----
        {
            float d0 = 0.f, d1 = 0.f, d2 = 0.f;
            if (rd_R) {
                const _Float16* hrow = h2s2[R & 1];
#pragma unroll
                for (int dx = 0; dx < 3; ++dx) {
                    int xim = X0 + c3px + dx - 1;
                    if (xim >= 0 && xim < WW) {
                        int lpx = c3px + 8 + dx - 1;
                        int sp = c3h ^ ((lpx >> 2) & 1);
                        h16x8 v = *(const h16x8*)(hrow + lpx * 16 + sp * 8);
#pragma unroll
                        for (int q = 0; q < 4; ++q) {
                            h16x2 pv = { v[2 * q], v[2 * q + 1] };
                            d0 = __builtin_amdgcn_fdot2(pv, w3s[(0 + dx) * 8 + 4 * c3h + q], d0, false);
                            d1 = __builtin_amdgcn_fdot2(pv, w3s[(3 + dx) * 8 + 4 * c3h + q], d1, false);
                            d2 = __builtin_amdgcn_fdot2(pv, w3s[(6 + dx) * 8 + 4 * c3h + q], d2, false);
                        }
                    }
                }
            }
            if (i >= 6) {
                float accv = accC3 + d2;
                float full = accv + __shfl_xor(accv, 1) + w3bias;
                if (c3h == 0) {
                    float sg = 1.f / (1.f + expf(-full));
                    float tf = 0.7f * tgv + 0.3f * sg;
                    outb[oOut] = fminf(fmaxf(tf, 0.f), 1.f);
                }
            }
            accC3 = accN + d1;
            accN = d0;
        }

        // ---- E: conv1 MFMA (Bv drained) + store h1 row r1 ----
        if (do_h1) {
            h16x8 w1[2][3];
#pragma unroll
            for (int cg = 0; cg < 2; ++cg)
#pragma unroll
                for (int t = 0; t < 3; ++t) w1[cg][t] = wf1s[(cg * 3 + t) * 64 + lane];
            _Float16* h1row = h1s[s3(r1)];
            f32x4 b1lo = *(const f32x4*)(sB + gq * 4);
            f32x4 b1hi = *(const f32x4*)(sB + 16 + gq * 4);
            __builtin_amdgcn_s_setprio(1);
#pragma unroll
            for (int k = 0; k < 2; ++k) {
                f32x4 a1[2] = { b1lo, b1hi };
#pragma unroll
                for (int t = 0; t < 3; ++t)
#pragma unroll
                    for (int cg = 0; cg < 2; ++cg)
                        a1[cg] = __builtin_amdgcn_mfma_f32_16x16x32_f16(w1[cg][t], Bv[k][t], a1[cg], 0, 0, 0);
                int lp = (g0 + k) * 16 + j;
#pragma unroll
                for (int cg = 0; cg < 2; ++cg) {
                    h16x4 o;
#pragma unroll
                    for (int r = 0; r < 4; ++r) o[r] = (_Float16)fmaxf(a1[cg][r], 0.f);
                    st_h1(h1row, lp, cg * 4 + gq, o);
                }
            }
            if (wave == 5) {                      // g16 conv1 (off wave 4)
                f32x4 a1[2] = { b1lo, b1hi };
#pragma unroll
                for (int t = 0; t < 3; ++t)
#pragma unroll
                    for (int cg = 0; cg < 2; ++cg)
                        a1[cg] = __builtin_amdgcn_mfma_f32_16x16x32_f16(w1[cg][t], Bg[t], a1[cg], 0, 0, 0);
                int lp = 256 + j;
#pragma unroll
                for (int cg = 0; cg < 2; ++cg) {
                    h16x4 o;
#pragma unroll
                    for (int r = 0; r < 4; ++r) o[r] = (_Float16)fmaxf(a1[cg][r], 0.f);
                    st_h1(h1row, lp, cg * 4 + gq, o);
                }
            }
            __builtin_amdgcn_s_setprio(0);
        }
        __syncthreads();
    }
}

extern "C" void kernel_launch(void* const* d_in, const int* in_sizes, int n_in,
                              void* d_out, int out_size, void* d_ws, size_t ws_size,
                              hipStream_t stream) {
    const float* I    = (const float*)d_in[0];
    const float* t0   = (const float*)d_in[1];
    const float* dark = (const float*)d_in[2];
    const float* A    = (const float*)d_in[3];
    const float* W1   = (const float*)d_in[4];
    const float* b1   = (const float*)d_in[5];
    const float* W2   = (const float*)d_in[6];
    const float* b2   = (const float*)d_in[7];
    const float* W3   = (const float*)d_in[8];
    const float* b3   = (const float*)d_in[9];
    float* out = (float*)d_out;
    float* ws  = (float*)d_ws;

    const size_t P = (size_t)BB * HW;       // 2M floats = 8 MB
    _Float16* feats = (_Float16*)(ws + P);      // [P,5P)   fp16 [B][HW][8]
    float* g        = ws + 5 * P;               // [5P,6P)  fp32
    h16x4* hq       = (h16x4*)(ws + 6 * P);     // [6P,8P)  8B/px
    h16x2* ab       = (h16x2*)(ws + 8 * P);     // [8P,9P)  4B/px
    h16x2* hab      = (h16x2*)(ws + 9 * P);     // [9P,10P) 4B/px
    _Float16* wf1   = (_Float16*)(ws + 10 * P); // 3072 halves
    _Float16* wf2   = wf1 + 6 * 64 * 8;         // 4608 halves

    k_gray_hbox4<<<BB * HH, 256, 0, stream>>>(I, t0, dark, g, hq, feats, W1, W2, wf1, wf2);
    dim3 gv(WW / 256, BB, HH / SEG);
    k_vbox4_ab<<<gv, 256, 0, stream>>>(hq, ab);
    k_hbox2<<<BB * HH, 256, 0, stream>>>(ab, hab);
    k_vbox2_tg<<<gv, 256, 0, stream>>>(hab, g, A, feats);

    dim3 gf(64, BB);                        // 32 y-tiles x 2 x-halves x 8 batches
    k_cnn_fused<<<gf, 512, 0, stream>>>(feats, wf1, wf2, b1, b2, W3, b3, out);
}